// Round 6
// baseline (992.032 us; speedup 1.0000x reference)
//
#include <hip/hip_runtime.h>
#include <math.h>

#define D 128
#define PROJ_EPS 1e-5f
#define MAX_NN (1.0f - PROJ_EPS)
#define MIN_NORM 1e-15f
#define ROWS_PER_BLOCK 2048
#define NDEG 64

struct __align__(8) Edge { int c; float v; };

typedef __attribute__((ext_vector_type(8))) short bf16x8;
typedef __attribute__((ext_vector_type(4))) float f32x4;

__device__ inline unsigned short f2bf(float f) {
    unsigned u = __float_as_uint(f);
    unsigned r = (u + 0x7FFFu + ((u >> 16) & 1u)) >> 16;
    return (unsigned short)r;
}
__device__ inline float bf2f(unsigned short h) {
    return __uint_as_float(((unsigned)h) << 16);
}

__device__ inline float wave_sum(float v) {
#pragma unroll
    for (int off = 32; off; off >>= 1) v += __shfl_xor(v, off, 64);
    return v;
}
__device__ inline float gsum(float v) {
#pragma unroll
    for (int off = 16; off; off >>= 1) v += __shfl_xor(v, off, 64);
    return v;
}
__device__ inline void gsum2(float& a, float& b) {
#pragma unroll
    for (int off = 16; off; off >>= 1) {
        a += __shfl_xor(a, off, 64);
        b += __shfl_xor(b, off, 64);
    }
}
__device__ inline float frcp(float x) { return __builtin_amdgcn_rcpf(x); }
__device__ inline float fsqrt_(float x) { return __builtin_amdgcn_sqrtf(x); }
__device__ inline float tanh_pos(float x) {
    float e = __expf(-2.f * x);
    return (1.f - e) * frcp(1.f + e);
}
__device__ inline float tanh_sgn(float x) {
    float ax = fabsf(x);
    float e = __expf(-2.f * ax);
    float r = (1.f - e) * frcp(1.f + e);
    return copysignf(r, x);
}
__device__ inline float atanh_clip(float x) {
    return 0.5f * __logf((1.f + x) * frcp(1.f - x));
}

// ---- packed-f32 pair ops (CDNA4 full-rate fp32 is the packed path) ----
__device__ inline float2 mk2(float a, float b) { float2 r; r.x = a; r.y = b; return r; }
__device__ inline float2 bc2(float a) { return mk2(a, a); }
__device__ inline float2 pk_fma2(float2 a, float2 b, float2 c) {
    float2 d;
    asm("v_pk_fma_f32 %0, %1, %2, %3" : "=v"(d) : "v"(a), "v"(b), "v"(c));
    return d;
}
__device__ inline float2 pk_mul2(float2 a, float2 b) {
    float2 d;
    asm("v_pk_mul_f32 %0, %1, %2" : "=v"(d) : "v"(a), "v"(b));
    return d;
}
// unpack 2 bf16 (packed in u32, low = even elem) to float2
__device__ inline float2 up2(unsigned u) {
    uint2 t; t.x = u << 16; t.y = u & 0xffff0000u;
    float2 r; r.x = __uint_as_float(t.x); r.y = __uint_as_float(t.y);
    return r;
}

// ---------------- CSR build ----------------
__global__ void hist_kernel(const int* __restrict__ rows, int* __restrict__ counts, int e) {
    int i = blockIdx.x * blockDim.x + threadIdx.x;
    if (i < e) atomicAdd(&counts[rows[i]], 1);
}

__global__ __launch_bounds__(256) void partial_kernel(const int* __restrict__ counts,
                                                      int* __restrict__ partials, int n) {
    int t = threadIdx.x;
    int start = blockIdx.x * ROWS_PER_BLOCK + t * 8;
    int s = 0;
#pragma unroll
    for (int j = 0; j < 8; ++j) {
        int i = start + j;
        if (i < n) s += counts[i];
    }
    int lane = t & 63, wv = t >> 6;
#pragma unroll
    for (int o = 32; o; o >>= 1) s += __shfl_xor(s, o, 64);
    __shared__ int wsum[4];
    if (lane == 0) wsum[wv] = s;
    __syncthreads();
    if (t == 0) partials[blockIdx.x] = wsum[0] + wsum[1] + wsum[2] + wsum[3];
}

__global__ void scan_partials(int* __restrict__ partials, int npart) {
    __shared__ int buf[1024];
    int t = threadIdx.x;
    int v = (t < npart) ? partials[t] : 0;
    buf[t] = v;
    __syncthreads();
    for (int o = 1; o < 1024; o <<= 1) {
        int x = (t >= o) ? buf[t - o] : 0;
        __syncthreads();
        buf[t] += x;
        __syncthreads();
    }
    if (t < npart) partials[t] = buf[t] - v;
}

__global__ __launch_bounds__(256) void rowptr_kernel(const int* __restrict__ counts,
                                                     const int* __restrict__ partials,
                                                     int* __restrict__ row_ptr,
                                                     int* __restrict__ cursor, int n, int e) {
    int t = threadIdx.x;
    int start = blockIdx.x * ROWS_PER_BLOCK + t * 8;
    int c[8];
    int s = 0;
#pragma unroll
    for (int j = 0; j < 8; ++j) {
        int i = start + j;
        c[j] = (i < n) ? counts[i] : 0;
        s += c[j];
    }
    int lane = t & 63, wv = t >> 6;
    int inc = s;
#pragma unroll
    for (int o = 1; o < 64; o <<= 1) {
        int tt = __shfl_up(inc, o, 64);
        if (lane >= o) inc += tt;
    }
    __shared__ int wsum[4];
    if (lane == 63) wsum[wv] = inc;
    __syncthreads();
    if (t == 0) {
        int acc = 0;
        for (int w = 0; w < 4; ++w) { int tmp = wsum[w]; wsum[w] = acc; acc += tmp; }
    }
    __syncthreads();
    int run = partials[blockIdx.x] + wsum[wv] + (inc - s);
#pragma unroll
    for (int j = 0; j < 8; ++j) {
        int i = start + j;
        if (i < n) {
            row_ptr[i] = run;
            cursor[i] = run;
            run += c[j];
        }
    }
    if (blockIdx.x == 0 && t == 0) row_ptr[n] = e;
}

__global__ void scatter_kernel(const int* __restrict__ rows, const int* __restrict__ cols,
                               const float* __restrict__ vals, int* __restrict__ cursor,
                               Edge* __restrict__ eds, int e) {
    int i = blockIdx.x * blockDim.x + threadIdx.x;
    if (i < e) {
        int r = rows[i];
        int pos = atomicAdd(&cursor[r], 1);
        Edge ed; ed.c = cols[i]; ed.v = vals[i];
        eds[pos] = ed;
    }
}

// ---------------- degree sort (counting sort, schedule-balance only) ----------------
__global__ void deg_hist(const int* __restrict__ counts, int* __restrict__ dh, int n) {
    int i = blockIdx.x * blockDim.x + threadIdx.x;
    if (i < n) atomicAdd(&dh[min(counts[i], NDEG - 1)], 1);
}
__global__ void deg_scan(const int* __restrict__ dh, int* __restrict__ dcur) {
    if (threadIdx.x == 0) {
        int s = 0;
        for (int j = 0; j < NDEG; ++j) { int v = dh[j]; dcur[j] = s; s += v; }
    }
}
__global__ void deg_scatter(const int* __restrict__ counts, int* __restrict__ dcur,
                            int* __restrict__ perm, int n) {
    int i = blockIdx.x * blockDim.x + threadIdx.x;
    if (i < n) {
        int d = min(counts[i], NDEG - 1);
        int p = atomicAdd(&dcur[d], 1);
        perm[p] = i;
    }
}

// ---------------- init: x = proj(ent), logscale, xnorm2 ----------------
__global__ __launch_bounds__(256) void proj_init(const float* __restrict__ ent,
                                                 float* __restrict__ x,
                                                 float* __restrict__ logscale,
                                                 float* __restrict__ xnorm2, int n) {
    int wid = (int)((blockIdx.x * (size_t)blockDim.x + threadIdx.x) >> 6);
    int lane = threadIdx.x & 63;
    if (wid >= n) return;
    float2 v = *(const float2*)(ent + (size_t)wid * D + 2 * lane);
    float nrm = sqrtf(wave_sum(v.x * v.x + v.y * v.y));
    float scale = (nrm > MAX_NN) ? MAX_NN / fmaxf(nrm, MIN_NORM) : 1.0f;
    float px = v.x * scale, py = v.y * scale;
    float n2 = fmaxf(sqrtf(wave_sum(px * px + py * py)), MIN_NORM);
    float nc = fminf(fmaxf(n2, MIN_NORM), MAX_NN);
    float ls = atanhf(nc) / n2;
    *(float2*)(x + (size_t)wid * D + 2 * lane) = make_float2(px, py);
    if (lane == 0) { logscale[wid] = ls; xnorm2[wid] = n2 * n2; }
}

// ---------------- per-layer bias precompute ----------------
__global__ void bias_prep(const float* __restrict__ bias, float* __restrict__ bh,
                          float* __restrict__ vvb) {
    int l = blockIdx.x;
    int lane = threadIdx.x;
    float2 b2 = *(const float2*)(bias + (size_t)l * D + 2 * lane);
    float nn = fmaxf(sqrtf(wave_sum(b2.x * b2.x + b2.y * b2.y)), MIN_NORM);
    float s = tanhf(nn) / nn;
    float bx = b2.x * s, by = b2.y * s;
    float pn = sqrtf(wave_sum(bx * bx + by * by));
    float sc = (pn > MAX_NN) ? MAX_NN / fmaxf(pn, MIN_NORM) : 1.0f;
    bx *= sc; by *= sc;
    float vv = wave_sum(bx * bx + by * by);
    *(float2*)(bh + (size_t)l * D + 2 * lane) = make_float2(bx, by);
    if (lane == 0) vvb[l] = vv;
}

// ---------------- m = (logscale[row] * x[row]) @ W via bf16 MFMA (hi/lo), bf16 output ----
__global__ __launch_bounds__(256, 3) void logmap_gemm(const float* __restrict__ x,
                                                      const float* __restrict__ logscale,
                                                      const float* __restrict__ W,
                                                      unsigned short* __restrict__ m, int n,
                                                      int ntiles) {
    __shared__ char lds[16384];
    const int t = threadIdx.x;
    const int wid = t >> 6, lane = t & 63;
    const int lcol = lane & 15, lkg = lane >> 4;
    const int colbase = wid * 32;

    bf16x8 Bh[4][2], Bl[4][2];
#pragma unroll
    for (int ki = 0; ki < 4; ++ki) {
#pragma unroll
        for (int cf = 0; cf < 2; ++cf) {
            const float* wp = W + (size_t)(ki * 32 + lkg * 8) * D + colbase + cf * 16 + lcol;
#pragma unroll
            for (int e = 0; e < 8; ++e) {
                float f = wp[(size_t)e * D];
                unsigned short h = f2bf(f);
                Bh[ki][cf][e] = (short)h;
                Bl[ki][cf][e] = (short)f2bf(f - bf2f(h));
            }
        }
    }

    for (int tile = blockIdx.x; tile < ntiles; tile += gridDim.x) {
        const int row0 = tile * 32;
        __syncthreads();
#pragma unroll
        for (int p = t; p < 512; p += 256) {
            int fi = p >> 6, ln = p & 63;
            int rf = fi >> 2, ki = fi & 3;
            int row = row0 + rf * 16 + (ln & 15);
            int k0 = ki * 32 + (ln >> 4) * 8;
            float v[8];
            if (row < n) {
                float ls = logscale[row];
                const float* xp = x + (size_t)row * D + k0;
                *(float4*)&v[0] = *(const float4*)xp;
                *(float4*)&v[4] = *(const float4*)(xp + 4);
#pragma unroll
                for (int e = 0; e < 8; ++e) v[e] *= ls;
            } else {
#pragma unroll
                for (int e = 0; e < 8; ++e) v[e] = 0.f;
            }
            bf16x8 hi, lo;
#pragma unroll
            for (int e = 0; e < 8; ++e) {
                unsigned short h = f2bf(v[e]);
                hi[e] = (short)h;
                lo[e] = (short)f2bf(v[e] - bf2f(h));
            }
            *(bf16x8*)(lds + fi * 1024 + ln * 16) = hi;
            *(bf16x8*)(lds + 8192 + fi * 1024 + ln * 16) = lo;
        }
        __syncthreads();

        f32x4 acc[2][2];
#pragma unroll
        for (int rf = 0; rf < 2; ++rf)
#pragma unroll
            for (int cf = 0; cf < 2; ++cf) acc[rf][cf] = (f32x4){0.f, 0.f, 0.f, 0.f};

#pragma unroll
        for (int ki = 0; ki < 4; ++ki) {
            bf16x8 Ah[2], Al[2];
#pragma unroll
            for (int rf = 0; rf < 2; ++rf) {
                Ah[rf] = *(const bf16x8*)(lds + (rf * 4 + ki) * 1024 + lane * 16);
                Al[rf] = *(const bf16x8*)(lds + 8192 + (rf * 4 + ki) * 1024 + lane * 16);
            }
#pragma unroll
            for (int rf = 0; rf < 2; ++rf)
#pragma unroll
                for (int cf = 0; cf < 2; ++cf) {
                    acc[rf][cf] = __builtin_amdgcn_mfma_f32_16x16x32_bf16(Ah[rf], Bh[ki][cf], acc[rf][cf], 0, 0, 0);
                    acc[rf][cf] = __builtin_amdgcn_mfma_f32_16x16x32_bf16(Ah[rf], Bl[ki][cf], acc[rf][cf], 0, 0, 0);
                    acc[rf][cf] = __builtin_amdgcn_mfma_f32_16x16x32_bf16(Al[rf], Bh[ki][cf], acc[rf][cf], 0, 0, 0);
                }
        }

#pragma unroll
        for (int rf = 0; rf < 2; ++rf)
#pragma unroll
            for (int cf = 0; cf < 2; ++cf)
#pragma unroll
                for (int r = 0; r < 4; ++r) {
                    int row = row0 + rf * 16 + lkg * 4 + r;
                    if (row < n)
                        m[(size_t)row * D + colbase + cf * 16 + lcol] = f2bf(acc[rf][cf][r]);
                }
    }
}

// ---------------- aggregate + epilogue: 2 rows/wave, degree-paired, packed-f32 ----------
__global__ __launch_bounds__(256) void aggregate(const unsigned short* __restrict__ m,
                                                 const int* __restrict__ row_ptr,
                                                 const Edge* __restrict__ eds,
                                                 const int* __restrict__ perm,
                                                 const float* __restrict__ bh,
                                                 const float* __restrict__ vvb_p,
                                                 float* __restrict__ x,
                                                 float* __restrict__ logscale,
                                                 float* __restrict__ xnorm2,
                                                 int n, int use_act, int last) {
    int wv = (int)((blockIdx.x * (size_t)blockDim.x + threadIdx.x) >> 6);
    int lane = threadIdx.x & 63;
    int half = lane >> 5, li = lane & 31;
    if (wv * 2 >= n) return;
    int idx = wv * 2 + half;
    bool active = (idx < n);
    int r = active ? perm[idx] : 0;

    int beg = 0, end = 0;
    if (active) { beg = row_ptr[r]; end = row_ptr[r + 1]; }

    const char* mB = (const char*)m + ((size_t)li << 3);
    float2 A01 = bc2(0.f), A23 = bc2(0.f);
    int e = beg;
    for (; e + 8 <= end; e += 8) {
#pragma unroll
        for (int j = 0; j < 8; j += 4) {
            Edge e0 = eds[e + j], e1 = eds[e + j + 1], e2 = eds[e + j + 2], e3 = eds[e + j + 3];
            uint2 g0 = *(const uint2*)(mB + ((size_t)(unsigned)e0.c << 8));
            uint2 g1 = *(const uint2*)(mB + ((size_t)(unsigned)e1.c << 8));
            uint2 g2 = *(const uint2*)(mB + ((size_t)(unsigned)e2.c << 8));
            uint2 g3 = *(const uint2*)(mB + ((size_t)(unsigned)e3.c << 8));
            A01 = pk_fma2(up2(g0.x), bc2(e0.v), A01); A23 = pk_fma2(up2(g0.y), bc2(e0.v), A23);
            A01 = pk_fma2(up2(g1.x), bc2(e1.v), A01); A23 = pk_fma2(up2(g1.y), bc2(e1.v), A23);
            A01 = pk_fma2(up2(g2.x), bc2(e2.v), A01); A23 = pk_fma2(up2(g2.y), bc2(e2.v), A23);
            A01 = pk_fma2(up2(g3.x), bc2(e3.v), A01); A23 = pk_fma2(up2(g3.y), bc2(e3.v), A23);
        }
    }
    for (; e < end; ++e) {
        Edge ee = eds[e];
        uint2 g = *(const uint2*)(mB + ((size_t)(unsigned)ee.c << 8));
        A01 = pk_fma2(up2(g.x), bc2(ee.v), A01); A23 = pk_fma2(up2(g.y), bc2(ee.v), A23);
    }

    float4 bhv4 = *(const float4*)(bh + 4 * li);
    float2 b01 = mk2(bhv4.x, bhv4.y), b23 = mk2(bhv4.z, bhv4.w);
    float vvb = *vvb_p;

    float2 daa = pk_fma2(A23, A23, pk_mul2(A01, A01));
    float2 dab = pk_fma2(A23, b23, pk_mul2(A01, b01));
    float saa = daa.x + daa.y, sab = dab.x + dab.y;
    gsum2(saa, sab);

    float na = fmaxf(fsqrt_(saa), MIN_NORM);
    float th = tanh_pos(na);
    float s1 = th * frcp(na);
    float nh = th;
    if (th > MAX_NN) { s1 *= MAX_NN * frcp(th); nh = MAX_NN; }
    float2 H01 = pk_mul2(A01, bc2(s1)), H23 = pk_mul2(A23, bc2(s1));
    float uu = nh * nh;
    float uv = s1 * sab;

    float ca = 1.f + 2.f * uv + vvb;
    float cb = 1.f - uu;
    float den = fmaxf(1.f + 2.f * uv + uu * vvb, MIN_NORM);
    float nsq = fmaxf(ca * ca * uu + 2.f * ca * cb * uv + cb * cb * vvb, 0.f);
    float rden = frcp(den);
    float n2 = fsqrt_(nsq) * rden;
    float s2 = rden;
    if (n2 > MAX_NN) { s2 *= MAX_NN * frcp(n2); n2 = MAX_NN; }
    float2 P01 = pk_mul2(pk_fma2(H01, bc2(ca), pk_mul2(b01, bc2(cb))), bc2(s2));
    float2 P23 = pk_mul2(pk_fma2(H23, bc2(ca), pk_mul2(b23, bc2(cb))), bc2(s2));

    float4 xo4 = active ? *(const float4*)(x + (size_t)r * D + 4 * li)
                        : make_float4(0.f, 0.f, 0.f, 0.f);
    float2 xo01 = mk2(xo4.x, xo4.y), xo23 = mk2(xo4.z, xo4.w);

    float2 Q01, Q23;
    float uu3, uv3;
    if (use_act) {
        float nnv = fmaxf(n2, MIN_NORM);
        float nc = fminf(fmaxf(n2, MIN_NORM), MAX_NN);
        float ls2 = atanh_clip(nc) * frcp(nnv);
        float2 Z01 = pk_mul2(P01, bc2(ls2)), Z23 = pk_mul2(P23, bc2(ls2));
        float2 T01 = mk2(tanh_sgn(Z01.x), tanh_sgn(Z01.y));
        float2 T23 = mk2(tanh_sgn(Z23.x), tanh_sgn(Z23.y));
        float2 dtt = pk_fma2(T23, T23, pk_mul2(T01, T01));
        float2 dtx = pk_fma2(T23, xo23, pk_mul2(T01, xo01));
        float stt = dtt.x + dtt.y, stx = dtx.x + dtx.y;
        gsum2(stt, stx);
        float n3 = fmaxf(fsqrt_(stt), MIN_NORM);
        float th3 = tanh_pos(n3);
        float s3 = th3 * frcp(n3);
        float nh3 = th3;
        if (th3 > MAX_NN) { s3 *= MAX_NN * frcp(th3); nh3 = MAX_NN; }
        Q01 = pk_mul2(T01, bc2(s3)); Q23 = pk_mul2(T23, bc2(s3));
        uu3 = nh3 * nh3;
        uv3 = s3 * stx;
    } else {
        float2 dpx = pk_fma2(P23, xo23, pk_mul2(P01, xo01));
        float suv = gsum(dpx.x + dpx.y);
        Q01 = P01; Q23 = P23;
        uu3 = n2 * n2;
        uv3 = suv;
    }

    float vv = active ? xnorm2[r] : 0.f;
    ca = 1.f + 2.f * uv3 + vv;
    cb = 1.f - uu3;
    den = fmaxf(1.f + 2.f * uv3 + uu3 * vv, MIN_NORM);
    nsq = fmaxf(ca * ca * uu3 + 2.f * ca * cb * uv3 + cb * cb * vv, 0.f);
    rden = frcp(den);
    float n4 = fsqrt_(nsq) * rden;
    float s4 = rden;
    if (n4 > MAX_NN) { s4 *= MAX_NN * frcp(n4); n4 = MAX_NN; }
    float2 O01 = pk_mul2(pk_fma2(Q01, bc2(ca), pk_mul2(xo01, bc2(cb))), bc2(s4));
    float2 O23 = pk_mul2(pk_fma2(Q23, bc2(ca), pk_mul2(xo23, bc2(cb))), bc2(s4));

    if (active) {
        *(float4*)(x + (size_t)r * D + 4 * li) = make_float4(O01.x, O01.y, O23.x, O23.y);
        if (li == 0) {
            xnorm2[r] = n4 * n4;
            if (!last) {
                float nnv = fmaxf(n4, MIN_NORM);
                float nc = fminf(fmaxf(n4, MIN_NORM), MAX_NN);
                logscale[r] = atanh_clip(nc) * frcp(nnv);
            }
        }
    }
}

extern "C" void kernel_launch(void* const* d_in, const int* in_sizes, int n_in,
                              void* d_out, int out_size, void* d_ws, size_t ws_size,
                              hipStream_t stream) {
    const float* ent  = (const float*)d_in[0];
    const float* W    = (const float*)d_in[1];
    const float* bias = (const float*)d_in[2];
    const int* rows   = (const int*)d_in[3];
    const int* cols   = (const int*)d_in[4];
    const float* vals = (const float*)d_in[5];
    float* x = (float*)d_out;

    const int n = in_sizes[0] / D;
    const int e = in_sizes[3];
    const int nlayers = in_sizes[1] / (D * D);
    const int npart = (n + ROWS_PER_BLOCK - 1) / ROWS_PER_BLOCK;
    const int ntiles = (n + 31) / 32;

    char* ws = (char*)d_ws;
    size_t off = 0;
    auto alloc = [&](size_t bytes) {
        void* p = ws + off;
        off += (bytes + 255) & ~(size_t)255;
        return p;
    };
    unsigned short* m = (unsigned short*)alloc((size_t)n * D * sizeof(unsigned short));
    float* logscale = (float*)alloc((size_t)n * sizeof(float));
    float* xnorm2   = (float*)alloc((size_t)n * sizeof(float));
    int*   counts   = (int*)alloc((size_t)n * sizeof(int));
    int*   row_ptr  = (int*)alloc((size_t)(n + 1) * sizeof(int));
    int*   cursor   = (int*)alloc((size_t)n * sizeof(int));
    int*   partials = (int*)alloc((size_t)(npart > 1024 ? npart : 1024) * sizeof(int));
    int*   dh       = (int*)alloc((size_t)NDEG * sizeof(int));
    int*   dcur     = (int*)alloc((size_t)NDEG * sizeof(int));
    int*   perm     = (int*)alloc((size_t)n * sizeof(int));
    float* bhb      = (float*)alloc((size_t)nlayers * D * sizeof(float));
    float* vvb      = (float*)alloc((size_t)nlayers * sizeof(float));
    Edge*  eds      = (Edge*)alloc((size_t)e * sizeof(Edge));

    hipMemsetAsync(counts, 0, (size_t)n * sizeof(int), stream);
    hipMemsetAsync(dh, 0, (size_t)NDEG * sizeof(int), stream);
    hist_kernel<<<(e + 255) / 256, 256, 0, stream>>>(rows, counts, e);
    partial_kernel<<<npart, 256, 0, stream>>>(counts, partials, n);
    scan_partials<<<1, 1024, 0, stream>>>(partials, npart);
    rowptr_kernel<<<npart, 256, 0, stream>>>(counts, partials, row_ptr, cursor, n, e);
    scatter_kernel<<<(e + 255) / 256, 256, 0, stream>>>(rows, cols, vals, cursor, eds, e);
    deg_hist<<<(n + 255) / 256, 256, 0, stream>>>(counts, dh, n);
    deg_scan<<<1, 64, 0, stream>>>(dh, dcur);
    deg_scatter<<<(n + 255) / 256, 256, 0, stream>>>(counts, dcur, perm, n);

    bias_prep<<<nlayers, 64, 0, stream>>>(bias, bhb, vvb);
    proj_init<<<(n + 3) / 4, 256, 0, stream>>>(ent, x, logscale, xnorm2, n);

    for (int l = 0; l < nlayers; ++l) {
        logmap_gemm<<<782, 256, 0, stream>>>(x, logscale, W + (size_t)l * D * D, m, n, ntiles);
        int use_act = (l < nlayers - 1) ? 1 : 0;
        aggregate<<<(n + 7) / 8, 256, 0, stream>>>(m, row_ptr, eds, perm, bhb + (size_t)l * D,
                                                   vvb + l, x, logscale, xnorm2, n,
                                                   use_act, (l == nlayers - 1) ? 1 : 0);
    }
}

// Round 7
// 308.647 us; speedup vs baseline: 3.2141x; 3.2141x over previous
//
#include <hip/hip_runtime.h>
#include <math.h>

#define D 128
#define PROJ_EPS 1e-5f
#define MAX_NN (1.0f - PROJ_EPS)
#define MIN_NORM 1e-15f
#define ROWS_PER_BLOCK 2048
#define NDEG 64

struct __align__(8) Edge { int c; float v; };

typedef __attribute__((ext_vector_type(8))) short bf16x8;
typedef __attribute__((ext_vector_type(4))) float f32x4;

__device__ inline unsigned short f2bf(float f) {
    unsigned u = __float_as_uint(f);
    unsigned r = (u + 0x7FFFu + ((u >> 16) & 1u)) >> 16;
    return (unsigned short)r;
}
__device__ inline float bf2f(unsigned short h) {
    return __uint_as_float(((unsigned)h) << 16);
}

__device__ inline float wave_sum(float v) {
#pragma unroll
    for (int off = 32; off; off >>= 1) v += __shfl_xor(v, off, 64);
    return v;
}
__device__ inline float gsum(float v) {
#pragma unroll
    for (int off = 16; off; off >>= 1) v += __shfl_xor(v, off, 64);
    return v;
}
__device__ inline void gsum2(float& a, float& b) {
#pragma unroll
    for (int off = 16; off; off >>= 1) {
        a += __shfl_xor(a, off, 64);
        b += __shfl_xor(b, off, 64);
    }
}
__device__ inline float frcp(float x) { return __builtin_amdgcn_rcpf(x); }
__device__ inline float fsqrt_(float x) { return __builtin_amdgcn_sqrtf(x); }
__device__ inline float tanh_pos(float x) {
    float e = __expf(-2.f * x);
    return (1.f - e) * frcp(1.f + e);
}
__device__ inline float tanh_sgn(float x) {
    float ax = fabsf(x);
    float e = __expf(-2.f * ax);
    float r = (1.f - e) * frcp(1.f + e);
    return copysignf(r, x);
}
__device__ inline float atanh_clip(float x) {
    return 0.5f * __logf((1.f + x) * frcp(1.f - x));
}

// ---- packed-f32 pair ops ----
__device__ inline float2 mk2(float a, float b) { float2 r; r.x = a; r.y = b; return r; }
__device__ inline float2 bc2(float a) { return mk2(a, a); }
__device__ inline float2 pk_fma2(float2 a, float2 b, float2 c) {
    float2 d;
    asm("v_pk_fma_f32 %0, %1, %2, %3" : "=v"(d) : "v"(a), "v"(b), "v"(c));
    return d;
}
__device__ inline float2 pk_mul2(float2 a, float2 b) {
    float2 d;
    asm("v_pk_mul_f32 %0, %1, %2" : "=v"(d) : "v"(a), "v"(b));
    return d;
}
__device__ inline float2 up2(unsigned u) {
    uint2 t; t.x = u << 16; t.y = u & 0xffff0000u;
    float2 r; r.x = __uint_as_float(t.x); r.y = __uint_as_float(t.y);
    return r;
}

// ---------------- CSR build ----------------
__global__ void hist_kernel(const int* __restrict__ rows, int* __restrict__ counts, int e) {
    int i = blockIdx.x * blockDim.x + threadIdx.x;
    if (i < e) atomicAdd(&counts[rows[i]], 1);
}

__global__ __launch_bounds__(256) void partial_kernel(const int* __restrict__ counts,
                                                      int* __restrict__ partials, int n) {
    int t = threadIdx.x;
    int start = blockIdx.x * ROWS_PER_BLOCK + t * 8;
    int s = 0;
#pragma unroll
    for (int j = 0; j < 8; ++j) {
        int i = start + j;
        if (i < n) s += counts[i];
    }
    int lane = t & 63, wv = t >> 6;
#pragma unroll
    for (int o = 32; o; o >>= 1) s += __shfl_xor(s, o, 64);
    __shared__ int wsum[4];
    if (lane == 0) wsum[wv] = s;
    __syncthreads();
    if (t == 0) partials[blockIdx.x] = wsum[0] + wsum[1] + wsum[2] + wsum[3];
}

__global__ void scan_partials(int* __restrict__ partials, int npart) {
    __shared__ int buf[1024];
    int t = threadIdx.x;
    int v = (t < npart) ? partials[t] : 0;
    buf[t] = v;
    __syncthreads();
    for (int o = 1; o < 1024; o <<= 1) {
        int x = (t >= o) ? buf[t - o] : 0;
        __syncthreads();
        buf[t] += x;
        __syncthreads();
    }
    if (t < npart) partials[t] = buf[t] - v;
}

__global__ __launch_bounds__(256) void rowptr_kernel(const int* __restrict__ counts,
                                                     const int* __restrict__ partials,
                                                     int* __restrict__ row_ptr,
                                                     int* __restrict__ cursor, int n, int e) {
    int t = threadIdx.x;
    int start = blockIdx.x * ROWS_PER_BLOCK + t * 8;
    int c[8];
    int s = 0;
#pragma unroll
    for (int j = 0; j < 8; ++j) {
        int i = start + j;
        c[j] = (i < n) ? counts[i] : 0;
        s += c[j];
    }
    int lane = t & 63, wv = t >> 6;
    int inc = s;
#pragma unroll
    for (int o = 1; o < 64; o <<= 1) {
        int tt = __shfl_up(inc, o, 64);
        if (lane >= o) inc += tt;
    }
    __shared__ int wsum[4];
    if (lane == 63) wsum[wv] = inc;
    __syncthreads();
    if (t == 0) {
        int acc = 0;
        for (int w = 0; w < 4; ++w) { int tmp = wsum[w]; wsum[w] = acc; acc += tmp; }
    }
    __syncthreads();
    int run = partials[blockIdx.x] + wsum[wv] + (inc - s);
#pragma unroll
    for (int j = 0; j < 8; ++j) {
        int i = start + j;
        if (i < n) {
            row_ptr[i] = run;
            cursor[i] = run;
            run += c[j];
        }
    }
    if (blockIdx.x == 0 && t == 0) row_ptr[n] = e;
}

__global__ void scatter_kernel(const int* __restrict__ rows, const int* __restrict__ cols,
                               const float* __restrict__ vals, int* __restrict__ cursor,
                               Edge* __restrict__ eds, int e) {
    int i = blockIdx.x * blockDim.x + threadIdx.x;
    if (i < e) {
        int r = rows[i];
        int pos = atomicAdd(&cursor[r], 1);
        Edge ed; ed.c = cols[i]; ed.v = vals[i];
        eds[pos] = ed;
    }
}

// ---------------- degree sort (LDS-privatized counting sort) ----------------
__global__ __launch_bounds__(256) void deg_hist(const int* __restrict__ counts,
                                                int* __restrict__ dh, int n) {
    __shared__ int lh[NDEG];
    int t = threadIdx.x;
    if (t < NDEG) lh[t] = 0;
    __syncthreads();
    int start = blockIdx.x * ROWS_PER_BLOCK + t * 8;
#pragma unroll
    for (int j = 0; j < 8; ++j) {
        int i = start + j;
        if (i < n) atomicAdd(&lh[min(counts[i], NDEG - 1)], 1);
    }
    __syncthreads();
    if (t < NDEG && lh[t]) atomicAdd(&dh[t], lh[t]);
}

__global__ void deg_scan(const int* __restrict__ dh, int* __restrict__ dcur) {
    if (threadIdx.x == 0) {
        int s = 0;
        for (int j = 0; j < NDEG; ++j) { int v = dh[j]; dcur[j] = s; s += v; }
    }
}

// per-block: LDS hist -> reserve global chunk per bin -> write positions
__global__ __launch_bounds__(256) void deg_scatter(const int* __restrict__ counts,
                                                   int* __restrict__ dcur,
                                                   int* __restrict__ perm, int n) {
    __shared__ int lh[NDEG];
    __shared__ int lbase[NDEG];
    int t = threadIdx.x;
    if (t < NDEG) lh[t] = 0;
    __syncthreads();
    int start = blockIdx.x * ROWS_PER_BLOCK + t * 8;
    int d[8], lpos[8];
#pragma unroll
    for (int j = 0; j < 8; ++j) {
        int i = start + j;
        if (i < n) {
            d[j] = min(counts[i], NDEG - 1);
            lpos[j] = atomicAdd(&lh[d[j]], 1);
        } else d[j] = -1;
    }
    __syncthreads();
    if (t < NDEG) lbase[t] = lh[t] ? atomicAdd(&dcur[t], lh[t]) : 0;
    __syncthreads();
#pragma unroll
    for (int j = 0; j < 8; ++j) {
        if (d[j] >= 0) perm[lbase[d[j]] + lpos[j]] = start + j;
    }
}

// ---------------- init: x = proj(ent), logscale, xnorm2 ----------------
__global__ __launch_bounds__(256) void proj_init(const float* __restrict__ ent,
                                                 float* __restrict__ x,
                                                 float* __restrict__ logscale,
                                                 float* __restrict__ xnorm2, int n) {
    int wid = (int)((blockIdx.x * (size_t)blockDim.x + threadIdx.x) >> 6);
    int lane = threadIdx.x & 63;
    if (wid >= n) return;
    float2 v = *(const float2*)(ent + (size_t)wid * D + 2 * lane);
    float nrm = sqrtf(wave_sum(v.x * v.x + v.y * v.y));
    float scale = (nrm > MAX_NN) ? MAX_NN / fmaxf(nrm, MIN_NORM) : 1.0f;
    float px = v.x * scale, py = v.y * scale;
    float n2 = fmaxf(sqrtf(wave_sum(px * px + py * py)), MIN_NORM);
    float nc = fminf(fmaxf(n2, MIN_NORM), MAX_NN);
    float ls = atanhf(nc) / n2;
    *(float2*)(x + (size_t)wid * D + 2 * lane) = make_float2(px, py);
    if (lane == 0) { logscale[wid] = ls; xnorm2[wid] = n2 * n2; }
}

// ---------------- per-layer bias precompute ----------------
__global__ void bias_prep(const float* __restrict__ bias, float* __restrict__ bh,
                          float* __restrict__ vvb) {
    int l = blockIdx.x;
    int lane = threadIdx.x;
    float2 b2 = *(const float2*)(bias + (size_t)l * D + 2 * lane);
    float nn = fmaxf(sqrtf(wave_sum(b2.x * b2.x + b2.y * b2.y)), MIN_NORM);
    float s = tanhf(nn) / nn;
    float bx = b2.x * s, by = b2.y * s;
    float pn = sqrtf(wave_sum(bx * bx + by * by));
    float sc = (pn > MAX_NN) ? MAX_NN / fmaxf(pn, MIN_NORM) : 1.0f;
    bx *= sc; by *= sc;
    float vv = wave_sum(bx * bx + by * by);
    *(float2*)(bh + (size_t)l * D + 2 * lane) = make_float2(bx, by);
    if (lane == 0) vvb[l] = vv;
}

// ---------------- m = (logscale[row] * x[row]) @ W via bf16 MFMA (hi/lo), bf16 output ----
__global__ __launch_bounds__(256, 3) void logmap_gemm(const float* __restrict__ x,
                                                      const float* __restrict__ logscale,
                                                      const float* __restrict__ W,
                                                      unsigned short* __restrict__ m, int n,
                                                      int ntiles) {
    __shared__ char lds[16384];
    const int t = threadIdx.x;
    const int wid = t >> 6, lane = t & 63;
    const int lcol = lane & 15, lkg = lane >> 4;
    const int colbase = wid * 32;

    bf16x8 Bh[4][2], Bl[4][2];
#pragma unroll
    for (int ki = 0; ki < 4; ++ki) {
#pragma unroll
        for (int cf = 0; cf < 2; ++cf) {
            const float* wp = W + (size_t)(ki * 32 + lkg * 8) * D + colbase + cf * 16 + lcol;
#pragma unroll
            for (int e = 0; e < 8; ++e) {
                float f = wp[(size_t)e * D];
                unsigned short h = f2bf(f);
                Bh[ki][cf][e] = (short)h;
                Bl[ki][cf][e] = (short)f2bf(f - bf2f(h));
            }
        }
    }

    for (int tile = blockIdx.x; tile < ntiles; tile += gridDim.x) {
        const int row0 = tile * 32;
        __syncthreads();
#pragma unroll
        for (int p = t; p < 512; p += 256) {
            int fi = p >> 6, ln = p & 63;
            int rf = fi >> 2, ki = fi & 3;
            int row = row0 + rf * 16 + (ln & 15);
            int k0 = ki * 32 + (ln >> 4) * 8;
            float v[8];
            if (row < n) {
                float ls = logscale[row];
                const float* xp = x + (size_t)row * D + k0;
                *(float4*)&v[0] = *(const float4*)xp;
                *(float4*)&v[4] = *(const float4*)(xp + 4);
#pragma unroll
                for (int e = 0; e < 8; ++e) v[e] *= ls;
            } else {
#pragma unroll
                for (int e = 0; e < 8; ++e) v[e] = 0.f;
            }
            bf16x8 hi, lo;
#pragma unroll
            for (int e = 0; e < 8; ++e) {
                unsigned short h = f2bf(v[e]);
                hi[e] = (short)h;
                lo[e] = (short)f2bf(v[e] - bf2f(h));
            }
            *(bf16x8*)(lds + fi * 1024 + ln * 16) = hi;
            *(bf16x8*)(lds + 8192 + fi * 1024 + ln * 16) = lo;
        }
        __syncthreads();

        f32x4 acc[2][2];
#pragma unroll
        for (int rf = 0; rf < 2; ++rf)
#pragma unroll
            for (int cf = 0; cf < 2; ++cf) acc[rf][cf] = (f32x4){0.f, 0.f, 0.f, 0.f};

#pragma unroll
        for (int ki = 0; ki < 4; ++ki) {
            bf16x8 Ah[2], Al[2];
#pragma unroll
            for (int rf = 0; rf < 2; ++rf) {
                Ah[rf] = *(const bf16x8*)(lds + (rf * 4 + ki) * 1024 + lane * 16);
                Al[rf] = *(const bf16x8*)(lds + 8192 + (rf * 4 + ki) * 1024 + lane * 16);
            }
#pragma unroll
            for (int rf = 0; rf < 2; ++rf)
#pragma unroll
                for (int cf = 0; cf < 2; ++cf) {
                    acc[rf][cf] = __builtin_amdgcn_mfma_f32_16x16x32_bf16(Ah[rf], Bh[ki][cf], acc[rf][cf], 0, 0, 0);
                    acc[rf][cf] = __builtin_amdgcn_mfma_f32_16x16x32_bf16(Ah[rf], Bl[ki][cf], acc[rf][cf], 0, 0, 0);
                    acc[rf][cf] = __builtin_amdgcn_mfma_f32_16x16x32_bf16(Al[rf], Bh[ki][cf], acc[rf][cf], 0, 0, 0);
                }
        }

#pragma unroll
        for (int rf = 0; rf < 2; ++rf)
#pragma unroll
            for (int cf = 0; cf < 2; ++cf)
#pragma unroll
                for (int r = 0; r < 4; ++r) {
                    int row = row0 + rf * 16 + lkg * 4 + r;
                    if (row < n)
                        m[(size_t)row * D + colbase + cf * 16 + lcol] = f2bf(acc[rf][cf][r]);
                }
    }
}

// ---------------- aggregate + epilogue: 2 rows/wave, degree-paired, packed-f32 ----------
__global__ __launch_bounds__(256) void aggregate(const unsigned short* __restrict__ m,
                                                 const int* __restrict__ row_ptr,
                                                 const Edge* __restrict__ eds,
                                                 const int* __restrict__ perm,
                                                 const float* __restrict__ bh,
                                                 const float* __restrict__ vvb_p,
                                                 float* __restrict__ x,
                                                 float* __restrict__ logscale,
                                                 float* __restrict__ xnorm2,
                                                 int n, int use_act, int last) {
    int wv = (int)((blockIdx.x * (size_t)blockDim.x + threadIdx.x) >> 6);
    int lane = threadIdx.x & 63;
    int half = lane >> 5, li = lane & 31;
    if (wv * 2 >= n) return;
    int idx = wv * 2 + half;
    bool active = (idx < n);
    int r = active ? perm[idx] : 0;

    int beg = 0, end = 0;
    if (active) { beg = row_ptr[r]; end = row_ptr[r + 1]; }

    const char* mB = (const char*)m + ((size_t)li << 3);
    float2 A01 = bc2(0.f), A23 = bc2(0.f);
    int e = beg;
    for (; e + 8 <= end; e += 8) {
#pragma unroll
        for (int j = 0; j < 8; j += 4) {
            Edge e0 = eds[e + j], e1 = eds[e + j + 1], e2 = eds[e + j + 2], e3 = eds[e + j + 3];
            uint2 g0 = *(const uint2*)(mB + ((size_t)(unsigned)e0.c << 8));
            uint2 g1 = *(const uint2*)(mB + ((size_t)(unsigned)e1.c << 8));
            uint2 g2 = *(const uint2*)(mB + ((size_t)(unsigned)e2.c << 8));
            uint2 g3 = *(const uint2*)(mB + ((size_t)(unsigned)e3.c << 8));
            A01 = pk_fma2(up2(g0.x), bc2(e0.v), A01); A23 = pk_fma2(up2(g0.y), bc2(e0.v), A23);
            A01 = pk_fma2(up2(g1.x), bc2(e1.v), A01); A23 = pk_fma2(up2(g1.y), bc2(e1.v), A23);
            A01 = pk_fma2(up2(g2.x), bc2(e2.v), A01); A23 = pk_fma2(up2(g2.y), bc2(e2.v), A23);
            A01 = pk_fma2(up2(g3.x), bc2(e3.v), A01); A23 = pk_fma2(up2(g3.y), bc2(e3.v), A23);
        }
    }
    for (; e < end; ++e) {
        Edge ee = eds[e];
        uint2 g = *(const uint2*)(mB + ((size_t)(unsigned)ee.c << 8));
        A01 = pk_fma2(up2(g.x), bc2(ee.v), A01); A23 = pk_fma2(up2(g.y), bc2(ee.v), A23);
    }

    float4 bhv4 = *(const float4*)(bh + 4 * li);
    float2 b01 = mk2(bhv4.x, bhv4.y), b23 = mk2(bhv4.z, bhv4.w);
    float vvb = *vvb_p;

    float2 daa = pk_fma2(A23, A23, pk_mul2(A01, A01));
    float2 dab = pk_fma2(A23, b23, pk_mul2(A01, b01));
    float saa = daa.x + daa.y, sab = dab.x + dab.y;
    gsum2(saa, sab);

    float na = fmaxf(fsqrt_(saa), MIN_NORM);
    float th = tanh_pos(na);
    float s1 = th * frcp(na);
    float nh = th;
    if (th > MAX_NN) { s1 *= MAX_NN * frcp(th); nh = MAX_NN; }
    float2 H01 = pk_mul2(A01, bc2(s1)), H23 = pk_mul2(A23, bc2(s1));
    float uu = nh * nh;
    float uv = s1 * sab;

    float ca = 1.f + 2.f * uv + vvb;
    float cb = 1.f - uu;
    float den = fmaxf(1.f + 2.f * uv + uu * vvb, MIN_NORM);
    float nsq = fmaxf(ca * ca * uu + 2.f * ca * cb * uv + cb * cb * vvb, 0.f);
    float rden = frcp(den);
    float n2 = fsqrt_(nsq) * rden;
    float s2 = rden;
    if (n2 > MAX_NN) { s2 *= MAX_NN * frcp(n2); n2 = MAX_NN; }
    float2 P01 = pk_mul2(pk_fma2(H01, bc2(ca), pk_mul2(b01, bc2(cb))), bc2(s2));
    float2 P23 = pk_mul2(pk_fma2(H23, bc2(ca), pk_mul2(b23, bc2(cb))), bc2(s2));

    float4 xo4 = active ? *(const float4*)(x + (size_t)r * D + 4 * li)
                        : make_float4(0.f, 0.f, 0.f, 0.f);
    float2 xo01 = mk2(xo4.x, xo4.y), xo23 = mk2(xo4.z, xo4.w);

    float2 Q01, Q23;
    float uu3, uv3;
    if (use_act) {
        float nnv = fmaxf(n2, MIN_NORM);
        float nc = fminf(fmaxf(n2, MIN_NORM), MAX_NN);
        float ls2 = atanh_clip(nc) * frcp(nnv);
        float2 Z01 = pk_mul2(P01, bc2(ls2)), Z23 = pk_mul2(P23, bc2(ls2));
        float2 T01 = mk2(tanh_sgn(Z01.x), tanh_sgn(Z01.y));
        float2 T23 = mk2(tanh_sgn(Z23.x), tanh_sgn(Z23.y));
        float2 dtt = pk_fma2(T23, T23, pk_mul2(T01, T01));
        float2 dtx = pk_fma2(T23, xo23, pk_mul2(T01, xo01));
        float stt = dtt.x + dtt.y, stx = dtx.x + dtx.y;
        gsum2(stt, stx);
        float n3 = fmaxf(fsqrt_(stt), MIN_NORM);
        float th3 = tanh_pos(n3);
        float s3 = th3 * frcp(n3);
        float nh3 = th3;
        if (th3 > MAX_NN) { s3 *= MAX_NN * frcp(th3); nh3 = MAX_NN; }
        Q01 = pk_mul2(T01, bc2(s3)); Q23 = pk_mul2(T23, bc2(s3));
        uu3 = nh3 * nh3;
        uv3 = s3 * stx;
    } else {
        float2 dpx = pk_fma2(P23, xo23, pk_mul2(P01, xo01));
        float suv = gsum(dpx.x + dpx.y);
        Q01 = P01; Q23 = P23;
        uu3 = n2 * n2;
        uv3 = suv;
    }

    float vv = active ? xnorm2[r] : 0.f;
    ca = 1.f + 2.f * uv3 + vv;
    cb = 1.f - uu3;
    den = fmaxf(1.f + 2.f * uv3 + uu3 * vv, MIN_NORM);
    nsq = fmaxf(ca * ca * uu3 + 2.f * ca * cb * uv3 + cb * cb * vv, 0.f);
    rden = frcp(den);
    float n4 = fsqrt_(nsq) * rden;
    float s4 = rden;
    if (n4 > MAX_NN) { s4 *= MAX_NN * frcp(n4); n4 = MAX_NN; }
    float2 O01 = pk_mul2(pk_fma2(Q01, bc2(ca), pk_mul2(xo01, bc2(cb))), bc2(s4));
    float2 O23 = pk_mul2(pk_fma2(Q23, bc2(ca), pk_mul2(xo23, bc2(cb))), bc2(s4));

    if (active) {
        *(float4*)(x + (size_t)r * D + 4 * li) = make_float4(O01.x, O01.y, O23.x, O23.y);
        if (li == 0) {
            xnorm2[r] = n4 * n4;
            if (!last) {
                float nnv = fmaxf(n4, MIN_NORM);
                float nc = fminf(fmaxf(n4, MIN_NORM), MAX_NN);
                logscale[r] = atanh_clip(nc) * frcp(nnv);
            }
        }
    }
}

extern "C" void kernel_launch(void* const* d_in, const int* in_sizes, int n_in,
                              void* d_out, int out_size, void* d_ws, size_t ws_size,
                              hipStream_t stream) {
    const float* ent  = (const float*)d_in[0];
    const float* W    = (const float*)d_in[1];
    const float* bias = (const float*)d_in[2];
    const int* rows   = (const int*)d_in[3];
    const int* cols   = (const int*)d_in[4];
    const float* vals = (const float*)d_in[5];
    float* x = (float*)d_out;

    const int n = in_sizes[0] / D;
    const int e = in_sizes[3];
    const int nlayers = in_sizes[1] / (D * D);
    const int npart = (n + ROWS_PER_BLOCK - 1) / ROWS_PER_BLOCK;
    const int ntiles = (n + 31) / 32;

    char* ws = (char*)d_ws;
    size_t off = 0;
    auto alloc = [&](size_t bytes) {
        void* p = ws + off;
        off += (bytes + 255) & ~(size_t)255;
        return p;
    };
    unsigned short* m = (unsigned short*)alloc((size_t)n * D * sizeof(unsigned short));
    float* logscale = (float*)alloc((size_t)n * sizeof(float));
    float* xnorm2   = (float*)alloc((size_t)n * sizeof(float));
    int*   counts   = (int*)alloc((size_t)n * sizeof(int));
    int*   row_ptr  = (int*)alloc((size_t)(n + 1) * sizeof(int));
    int*   cursor   = (int*)alloc((size_t)n * sizeof(int));
    int*   partials = (int*)alloc((size_t)(npart > 1024 ? npart : 1024) * sizeof(int));
    int*   dh       = (int*)alloc((size_t)NDEG * sizeof(int));
    int*   dcur     = (int*)alloc((size_t)NDEG * sizeof(int));
    int*   perm     = (int*)alloc((size_t)n * sizeof(int));
    float* bhb      = (float*)alloc((size_t)nlayers * D * sizeof(float));
    float* vvb      = (float*)alloc((size_t)nlayers * sizeof(float));
    Edge*  eds      = (Edge*)alloc((size_t)e * sizeof(Edge));

    hipMemsetAsync(counts, 0, (size_t)n * sizeof(int), stream);
    hipMemsetAsync(dh, 0, (size_t)NDEG * sizeof(int), stream);
    hist_kernel<<<(e + 255) / 256, 256, 0, stream>>>(rows, counts, e);
    partial_kernel<<<npart, 256, 0, stream>>>(counts, partials, n);
    scan_partials<<<1, 1024, 0, stream>>>(partials, npart);
    rowptr_kernel<<<npart, 256, 0, stream>>>(counts, partials, row_ptr, cursor, n, e);
    scatter_kernel<<<(e + 255) / 256, 256, 0, stream>>>(rows, cols, vals, cursor, eds, e);
    deg_hist<<<npart, 256, 0, stream>>>(counts, dh, n);
    deg_scan<<<1, 64, 0, stream>>>(dh, dcur);
    deg_scatter<<<npart, 256, 0, stream>>>(counts, dcur, perm, n);

    bias_prep<<<nlayers, 64, 0, stream>>>(bias, bhb, vvb);
    proj_init<<<(n + 3) / 4, 256, 0, stream>>>(ent, x, logscale, xnorm2, n);

    for (int l = 0; l < nlayers; ++l) {
        logmap_gemm<<<782, 256, 0, stream>>>(x, logscale, W + (size_t)l * D * D, m, n, ntiles);
        int use_act = (l < nlayers - 1) ? 1 : 0;
        aggregate<<<(n + 7) / 8, 256, 0, stream>>>(m, row_ptr, eds, perm, bhb + (size_t)l * D,
                                                   vvb + l, x, logscale, xnorm2, n,
                                                   use_act, (l == nlayers - 1) ? 1 : 0);
    }
}

// Round 8
// 300.680 us; speedup vs baseline: 3.2993x; 1.0265x over previous
//
#include <hip/hip_runtime.h>
#include <math.h>

#define D 128
#define PROJ_EPS 1e-5f
#define MAX_NN (1.0f - PROJ_EPS)
#define MIN_NORM 1e-15f
#define ROWS_PER_BLOCK 2048
#define NDEG 64

struct __align__(8) Edge { int c; float v; };

typedef __attribute__((ext_vector_type(8))) short bf16x8;
typedef __attribute__((ext_vector_type(4))) float f32x4;

__device__ inline unsigned short f2bf(float f) {
    unsigned u = __float_as_uint(f);
    unsigned r = (u + 0x7FFFu + ((u >> 16) & 1u)) >> 16;
    return (unsigned short)r;
}
__device__ inline float bf2f(unsigned short h) {
    return __uint_as_float(((unsigned)h) << 16);
}

__device__ inline float wave_sum(float v) {
#pragma unroll
    for (int off = 32; off; off >>= 1) v += __shfl_xor(v, off, 64);
    return v;
}
__device__ inline float gsum(float v) {
#pragma unroll
    for (int off = 16; off; off >>= 1) v += __shfl_xor(v, off, 64);
    return v;
}
__device__ inline void gsum2(float& a, float& b) {
#pragma unroll
    for (int off = 16; off; off >>= 1) {
        a += __shfl_xor(a, off, 64);
        b += __shfl_xor(b, off, 64);
    }
}
__device__ inline float frcp(float x) { return __builtin_amdgcn_rcpf(x); }
__device__ inline float fsqrt_(float x) { return __builtin_amdgcn_sqrtf(x); }
__device__ inline float tanh_pos(float x) {
    float e = __expf(-2.f * x);
    return (1.f - e) * frcp(1.f + e);
}
__device__ inline float tanh_sgn(float x) {
    float ax = fabsf(x);
    float e = __expf(-2.f * ax);
    float r = (1.f - e) * frcp(1.f + e);
    return copysignf(r, x);
}
__device__ inline float atanh_clip(float x) {
    return 0.5f * __logf((1.f + x) * frcp(1.f - x));
}

// ---- packed-f32 pair ops ----
__device__ inline float2 mk2(float a, float b) { float2 r; r.x = a; r.y = b; return r; }
__device__ inline float2 bc2(float a) { return mk2(a, a); }
__device__ inline float2 pk_fma2(float2 a, float2 b, float2 c) {
    float2 d;
    asm("v_pk_fma_f32 %0, %1, %2, %3" : "=v"(d) : "v"(a), "v"(b), "v"(c));
    return d;
}
__device__ inline float2 pk_mul2(float2 a, float2 b) {
    float2 d;
    asm("v_pk_mul_f32 %0, %1, %2" : "=v"(d) : "v"(a), "v"(b));
    return d;
}
__device__ inline float2 up2(unsigned u) {
    uint2 t; t.x = u << 16; t.y = u & 0xffff0000u;
    float2 r; r.x = __uint_as_float(t.x); r.y = __uint_as_float(t.y);
    return r;
}

// ---------------- CSR build ----------------
__global__ void hist_kernel(const int* __restrict__ rows, int* __restrict__ counts, int e) {
    int i = blockIdx.x * blockDim.x + threadIdx.x;
    if (i < e) atomicAdd(&counts[rows[i]], 1);
}

__global__ __launch_bounds__(256) void partial_kernel(const int* __restrict__ counts,
                                                      int* __restrict__ partials, int n) {
    int t = threadIdx.x;
    int start = blockIdx.x * ROWS_PER_BLOCK + t * 8;
    int s = 0;
#pragma unroll
    for (int j = 0; j < 8; ++j) {
        int i = start + j;
        if (i < n) s += counts[i];
    }
    int lane = t & 63, wv = t >> 6;
#pragma unroll
    for (int o = 32; o; o >>= 1) s += __shfl_xor(s, o, 64);
    __shared__ int wsum[4];
    if (lane == 0) wsum[wv] = s;
    __syncthreads();
    if (t == 0) partials[blockIdx.x] = wsum[0] + wsum[1] + wsum[2] + wsum[3];
}

__global__ void scan_partials(int* __restrict__ partials, int npart) {
    __shared__ int buf[1024];
    int t = threadIdx.x;
    int v = (t < npart) ? partials[t] : 0;
    buf[t] = v;
    __syncthreads();
    for (int o = 1; o < 1024; o <<= 1) {
        int x = (t >= o) ? buf[t - o] : 0;
        __syncthreads();
        buf[t] += x;
        __syncthreads();
    }
    if (t < npart) partials[t] = buf[t] - v;
}

__global__ __launch_bounds__(256) void rowptr_kernel(const int* __restrict__ counts,
                                                     const int* __restrict__ partials,
                                                     int* __restrict__ row_ptr,
                                                     int* __restrict__ cursor, int n, int e) {
    int t = threadIdx.x;
    int start = blockIdx.x * ROWS_PER_BLOCK + t * 8;
    int c[8];
    int s = 0;
#pragma unroll
    for (int j = 0; j < 8; ++j) {
        int i = start + j;
        c[j] = (i < n) ? counts[i] : 0;
        s += c[j];
    }
    int lane = t & 63, wv = t >> 6;
    int inc = s;
#pragma unroll
    for (int o = 1; o < 64; o <<= 1) {
        int tt = __shfl_up(inc, o, 64);
        if (lane >= o) inc += tt;
    }
    __shared__ int wsum[4];
    if (lane == 63) wsum[wv] = inc;
    __syncthreads();
    if (t == 0) {
        int acc = 0;
        for (int w = 0; w < 4; ++w) { int tmp = wsum[w]; wsum[w] = acc; acc += tmp; }
    }
    __syncthreads();
    int run = partials[blockIdx.x] + wsum[wv] + (inc - s);
#pragma unroll
    for (int j = 0; j < 8; ++j) {
        int i = start + j;
        if (i < n) {
            row_ptr[i] = run;
            cursor[i] = run;
            run += c[j];
        }
    }
    if (blockIdx.x == 0 && t == 0) row_ptr[n] = e;
}

__global__ void scatter_kernel(const int* __restrict__ rows, const int* __restrict__ cols,
                               const float* __restrict__ vals, int* __restrict__ cursor,
                               Edge* __restrict__ eds, int e) {
    int i = blockIdx.x * blockDim.x + threadIdx.x;
    if (i < e) {
        int r = rows[i];
        int pos = atomicAdd(&cursor[r], 1);
        Edge ed; ed.c = cols[i]; ed.v = vals[i];
        eds[pos] = ed;
    }
}

// ---------------- block-local degree sort: perm within each 2048-row window ----------
__global__ __launch_bounds__(256) void block_degsort(const int* __restrict__ counts,
                                                     int* __restrict__ perm, int n) {
    __shared__ int lh[NDEG];
    __shared__ int lbase[NDEG];
    int t = threadIdx.x;
    int base = blockIdx.x * ROWS_PER_BLOCK;
    if (t < NDEG) lh[t] = 0;
    __syncthreads();
    int d[8], lpos[8];
#pragma unroll
    for (int j = 0; j < 8; ++j) {
        int i = base + t * 8 + j;
        if (i < n) {
            d[j] = min(counts[i], NDEG - 1);
            lpos[j] = atomicAdd(&lh[d[j]], 1);
        } else d[j] = -1;
    }
    __syncthreads();
    if (t == 0) {
        int s = 0;
        for (int j = 0; j < NDEG; ++j) { lbase[j] = s; s += lh[j]; }
    }
    __syncthreads();
#pragma unroll
    for (int j = 0; j < 8; ++j) {
        if (d[j] >= 0) perm[base + lbase[d[j]] + lpos[j]] = base + t * 8 + j;
    }
}

// ---------------- init: x = proj(ent), logscale, xnorm2 ----------------
__global__ __launch_bounds__(256) void proj_init(const float* __restrict__ ent,
                                                 float* __restrict__ x,
                                                 float* __restrict__ logscale,
                                                 float* __restrict__ xnorm2, int n) {
    int wid = (int)((blockIdx.x * (size_t)blockDim.x + threadIdx.x) >> 6);
    int lane = threadIdx.x & 63;
    if (wid >= n) return;
    float2 v = *(const float2*)(ent + (size_t)wid * D + 2 * lane);
    float nrm = sqrtf(wave_sum(v.x * v.x + v.y * v.y));
    float scale = (nrm > MAX_NN) ? MAX_NN / fmaxf(nrm, MIN_NORM) : 1.0f;
    float px = v.x * scale, py = v.y * scale;
    float n2 = fmaxf(sqrtf(wave_sum(px * px + py * py)), MIN_NORM);
    float nc = fminf(fmaxf(n2, MIN_NORM), MAX_NN);
    float ls = atanhf(nc) / n2;
    *(float2*)(x + (size_t)wid * D + 2 * lane) = make_float2(px, py);
    if (lane == 0) { logscale[wid] = ls; xnorm2[wid] = n2 * n2; }
}

// ---------------- per-layer bias precompute ----------------
__global__ void bias_prep(const float* __restrict__ bias, float* __restrict__ bh,
                          float* __restrict__ vvb) {
    int l = blockIdx.x;
    int lane = threadIdx.x;
    float2 b2 = *(const float2*)(bias + (size_t)l * D + 2 * lane);
    float nn = fmaxf(sqrtf(wave_sum(b2.x * b2.x + b2.y * b2.y)), MIN_NORM);
    float s = tanhf(nn) / nn;
    float bx = b2.x * s, by = b2.y * s;
    float pn = sqrtf(wave_sum(bx * bx + by * by));
    float sc = (pn > MAX_NN) ? MAX_NN / fmaxf(pn, MIN_NORM) : 1.0f;
    bx *= sc; by *= sc;
    float vv = wave_sum(bx * bx + by * by);
    *(float2*)(bh + (size_t)l * D + 2 * lane) = make_float2(bx, by);
    if (lane == 0) vvb[l] = vv;
}

// ---------------- m = (logscale[row] * x[row]) @ W via bf16 MFMA (hi/lo), bf16 output ----
__global__ __launch_bounds__(256, 3) void logmap_gemm(const float* __restrict__ x,
                                                      const float* __restrict__ logscale,
                                                      const float* __restrict__ W,
                                                      unsigned short* __restrict__ m, int n,
                                                      int ntiles) {
    __shared__ char lds[16384];
    const int t = threadIdx.x;
    const int wid = t >> 6, lane = t & 63;
    const int lcol = lane & 15, lkg = lane >> 4;
    const int colbase = wid * 32;

    bf16x8 Bh[4][2], Bl[4][2];
#pragma unroll
    for (int ki = 0; ki < 4; ++ki) {
#pragma unroll
        for (int cf = 0; cf < 2; ++cf) {
            const float* wp = W + (size_t)(ki * 32 + lkg * 8) * D + colbase + cf * 16 + lcol;
#pragma unroll
            for (int e = 0; e < 8; ++e) {
                float f = wp[(size_t)e * D];
                unsigned short h = f2bf(f);
                Bh[ki][cf][e] = (short)h;
                Bl[ki][cf][e] = (short)f2bf(f - bf2f(h));
            }
        }
    }

    for (int tile = blockIdx.x; tile < ntiles; tile += gridDim.x) {
        const int row0 = tile * 32;
        __syncthreads();
#pragma unroll
        for (int p = t; p < 512; p += 256) {
            int fi = p >> 6, ln = p & 63;
            int rf = fi >> 2, ki = fi & 3;
            int row = row0 + rf * 16 + (ln & 15);
            int k0 = ki * 32 + (ln >> 4) * 8;
            float v[8];
            if (row < n) {
                float ls = logscale[row];
                const float* xp = x + (size_t)row * D + k0;
                *(float4*)&v[0] = *(const float4*)xp;
                *(float4*)&v[4] = *(const float4*)(xp + 4);
#pragma unroll
                for (int e = 0; e < 8; ++e) v[e] *= ls;
            } else {
#pragma unroll
                for (int e = 0; e < 8; ++e) v[e] = 0.f;
            }
            bf16x8 hi, lo;
#pragma unroll
            for (int e = 0; e < 8; ++e) {
                unsigned short h = f2bf(v[e]);
                hi[e] = (short)h;
                lo[e] = (short)f2bf(v[e] - bf2f(h));
            }
            *(bf16x8*)(lds + fi * 1024 + ln * 16) = hi;
            *(bf16x8*)(lds + 8192 + fi * 1024 + ln * 16) = lo;
        }
        __syncthreads();

        f32x4 acc[2][2];
#pragma unroll
        for (int rf = 0; rf < 2; ++rf)
#pragma unroll
            for (int cf = 0; cf < 2; ++cf) acc[rf][cf] = (f32x4){0.f, 0.f, 0.f, 0.f};

#pragma unroll
        for (int ki = 0; ki < 4; ++ki) {
            bf16x8 Ah[2], Al[2];
#pragma unroll
            for (int rf = 0; rf < 2; ++rf) {
                Ah[rf] = *(const bf16x8*)(lds + (rf * 4 + ki) * 1024 + lane * 16);
                Al[rf] = *(const bf16x8*)(lds + 8192 + (rf * 4 + ki) * 1024 + lane * 16);
            }
#pragma unroll
            for (int rf = 0; rf < 2; ++rf)
#pragma unroll
                for (int cf = 0; cf < 2; ++cf) {
                    acc[rf][cf] = __builtin_amdgcn_mfma_f32_16x16x32_bf16(Ah[rf], Bh[ki][cf], acc[rf][cf], 0, 0, 0);
                    acc[rf][cf] = __builtin_amdgcn_mfma_f32_16x16x32_bf16(Ah[rf], Bl[ki][cf], acc[rf][cf], 0, 0, 0);
                    acc[rf][cf] = __builtin_amdgcn_mfma_f32_16x16x32_bf16(Al[rf], Bh[ki][cf], acc[rf][cf], 0, 0, 0);
                }
        }

#pragma unroll
        for (int rf = 0; rf < 2; ++rf)
#pragma unroll
            for (int cf = 0; cf < 2; ++cf)
#pragma unroll
                for (int r = 0; r < 4; ++r) {
                    int row = row0 + rf * 16 + lkg * 4 + r;
                    if (row < n)
                        m[(size_t)row * D + colbase + cf * 16 + lcol] = f2bf(acc[rf][cf][r]);
                }
    }
}

// ---------------- aggregate + epilogue: 2 rows/wave, block-local degree-paired ----------
__global__ __launch_bounds__(256) void aggregate(const unsigned short* __restrict__ m,
                                                 const int* __restrict__ row_ptr,
                                                 const Edge* __restrict__ eds,
                                                 const int* __restrict__ perm,
                                                 const float* __restrict__ bh,
                                                 const float* __restrict__ vvb_p,
                                                 float* __restrict__ x,
                                                 float* __restrict__ logscale,
                                                 float* __restrict__ xnorm2,
                                                 int n, int use_act, int last) {
    int wv = (int)((blockIdx.x * (size_t)blockDim.x + threadIdx.x) >> 6);
    int lane = threadIdx.x & 63;
    int half = lane >> 5, li = lane & 31;
    if (wv * 2 >= n) return;
    int idx = wv * 2 + half;
    bool active = (idx < n);
    int r = active ? perm[idx] : 0;

    int beg = 0, end = 0;
    if (active) { beg = row_ptr[r]; end = row_ptr[r + 1]; }

    const char* mB = (const char*)m + ((size_t)li << 3);
    float2 A01 = bc2(0.f), A23 = bc2(0.f);
    int e = beg;
    for (; e + 8 <= end; e += 8) {
#pragma unroll
        for (int j = 0; j < 8; j += 4) {
            Edge e0 = eds[e + j], e1 = eds[e + j + 1], e2 = eds[e + j + 2], e3 = eds[e + j + 3];
            uint2 g0 = *(const uint2*)(mB + ((size_t)(unsigned)e0.c << 8));
            uint2 g1 = *(const uint2*)(mB + ((size_t)(unsigned)e1.c << 8));
            uint2 g2 = *(const uint2*)(mB + ((size_t)(unsigned)e2.c << 8));
            uint2 g3 = *(const uint2*)(mB + ((size_t)(unsigned)e3.c << 8));
            A01 = pk_fma2(up2(g0.x), bc2(e0.v), A01); A23 = pk_fma2(up2(g0.y), bc2(e0.v), A23);
            A01 = pk_fma2(up2(g1.x), bc2(e1.v), A01); A23 = pk_fma2(up2(g1.y), bc2(e1.v), A23);
            A01 = pk_fma2(up2(g2.x), bc2(e2.v), A01); A23 = pk_fma2(up2(g2.y), bc2(e2.v), A23);
            A01 = pk_fma2(up2(g3.x), bc2(e3.v), A01); A23 = pk_fma2(up2(g3.y), bc2(e3.v), A23);
        }
    }
    for (; e < end; ++e) {
        Edge ee = eds[e];
        uint2 g = *(const uint2*)(mB + ((size_t)(unsigned)ee.c << 8));
        A01 = pk_fma2(up2(g.x), bc2(ee.v), A01); A23 = pk_fma2(up2(g.y), bc2(ee.v), A23);
    }

    float4 bhv4 = *(const float4*)(bh + 4 * li);
    float2 b01 = mk2(bhv4.x, bhv4.y), b23 = mk2(bhv4.z, bhv4.w);
    float vvb = *vvb_p;

    float2 daa = pk_fma2(A23, A23, pk_mul2(A01, A01));
    float2 dab = pk_fma2(A23, b23, pk_mul2(A01, b01));
    float saa = daa.x + daa.y, sab = dab.x + dab.y;
    gsum2(saa, sab);

    float na = fmaxf(fsqrt_(saa), MIN_NORM);
    float th = tanh_pos(na);
    float s1 = th * frcp(na);
    float nh = th;
    if (th > MAX_NN) { s1 *= MAX_NN * frcp(th); nh = MAX_NN; }
    float2 H01 = pk_mul2(A01, bc2(s1)), H23 = pk_mul2(A23, bc2(s1));
    float uu = nh * nh;
    float uv = s1 * sab;

    float ca = 1.f + 2.f * uv + vvb;
    float cb = 1.f - uu;
    float den = fmaxf(1.f + 2.f * uv + uu * vvb, MIN_NORM);
    float nsq = fmaxf(ca * ca * uu + 2.f * ca * cb * uv + cb * cb * vvb, 0.f);
    float rden = frcp(den);
    float n2 = fsqrt_(nsq) * rden;
    float s2 = rden;
    if (n2 > MAX_NN) { s2 *= MAX_NN * frcp(n2); n2 = MAX_NN; }
    float2 P01 = pk_mul2(pk_fma2(H01, bc2(ca), pk_mul2(b01, bc2(cb))), bc2(s2));
    float2 P23 = pk_mul2(pk_fma2(H23, bc2(ca), pk_mul2(b23, bc2(cb))), bc2(s2));

    float4 xo4 = active ? *(const float4*)(x + (size_t)r * D + 4 * li)
                        : make_float4(0.f, 0.f, 0.f, 0.f);
    float2 xo01 = mk2(xo4.x, xo4.y), xo23 = mk2(xo4.z, xo4.w);

    float2 Q01, Q23;
    float uu3, uv3;
    if (use_act) {
        float nnv = fmaxf(n2, MIN_NORM);
        float nc = fminf(fmaxf(n2, MIN_NORM), MAX_NN);
        float ls2 = atanh_clip(nc) * frcp(nnv);
        float2 Z01 = pk_mul2(P01, bc2(ls2)), Z23 = pk_mul2(P23, bc2(ls2));
        float2 T01 = mk2(tanh_sgn(Z01.x), tanh_sgn(Z01.y));
        float2 T23 = mk2(tanh_sgn(Z23.x), tanh_sgn(Z23.y));
        float2 dtt = pk_fma2(T23, T23, pk_mul2(T01, T01));
        float2 dtx = pk_fma2(T23, xo23, pk_mul2(T01, xo01));
        float stt = dtt.x + dtt.y, stx = dtx.x + dtx.y;
        gsum2(stt, stx);
        float n3 = fmaxf(fsqrt_(stt), MIN_NORM);
        float th3 = tanh_pos(n3);
        float s3 = th3 * frcp(n3);
        float nh3 = th3;
        if (th3 > MAX_NN) { s3 *= MAX_NN * frcp(th3); nh3 = MAX_NN; }
        Q01 = pk_mul2(T01, bc2(s3)); Q23 = pk_mul2(T23, bc2(s3));
        uu3 = nh3 * nh3;
        uv3 = s3 * stx;
    } else {
        float2 dpx = pk_fma2(P23, xo23, pk_mul2(P01, xo01));
        float suv = gsum(dpx.x + dpx.y);
        Q01 = P01; Q23 = P23;
        uu3 = n2 * n2;
        uv3 = suv;
    }

    float vv = active ? xnorm2[r] : 0.f;
    ca = 1.f + 2.f * uv3 + vv;
    cb = 1.f - uu3;
    den = fmaxf(1.f + 2.f * uv3 + uu3 * vv, MIN_NORM);
    nsq = fmaxf(ca * ca * uu3 + 2.f * ca * cb * uv3 + cb * cb * vv, 0.f);
    rden = frcp(den);
    float n4 = fsqrt_(nsq) * rden;
    float s4 = rden;
    if (n4 > MAX_NN) { s4 *= MAX_NN * frcp(n4); n4 = MAX_NN; }
    float2 O01 = pk_mul2(pk_fma2(Q01, bc2(ca), pk_mul2(xo01, bc2(cb))), bc2(s4));
    float2 O23 = pk_mul2(pk_fma2(Q23, bc2(ca), pk_mul2(xo23, bc2(cb))), bc2(s4));

    if (active) {
        *(float4*)(x + (size_t)r * D + 4 * li) = make_float4(O01.x, O01.y, O23.x, O23.y);
        if (li == 0) {
            xnorm2[r] = n4 * n4;
            if (!last) {
                float nnv = fmaxf(n4, MIN_NORM);
                float nc = fminf(fmaxf(n4, MIN_NORM), MAX_NN);
                logscale[r] = atanh_clip(nc) * frcp(nnv);
            }
        }
    }
}

extern "C" void kernel_launch(void* const* d_in, const int* in_sizes, int n_in,
                              void* d_out, int out_size, void* d_ws, size_t ws_size,
                              hipStream_t stream) {
    const float* ent  = (const float*)d_in[0];
    const float* W    = (const float*)d_in[1];
    const float* bias = (const float*)d_in[2];
    const int* rows   = (const int*)d_in[3];
    const int* cols   = (const int*)d_in[4];
    const float* vals = (const float*)d_in[5];
    float* x = (float*)d_out;

    const int n = in_sizes[0] / D;
    const int e = in_sizes[3];
    const int nlayers = in_sizes[1] / (D * D);
    const int npart = (n + ROWS_PER_BLOCK - 1) / ROWS_PER_BLOCK;
    const int ntiles = (n + 31) / 32;

    char* ws = (char*)d_ws;
    size_t off = 0;
    auto alloc = [&](size_t bytes) {
        void* p = ws + off;
        off += (bytes + 255) & ~(size_t)255;
        return p;
    };
    unsigned short* m = (unsigned short*)alloc((size_t)n * D * sizeof(unsigned short));
    float* logscale = (float*)alloc((size_t)n * sizeof(float));
    float* xnorm2   = (float*)alloc((size_t)n * sizeof(float));
    int*   counts   = (int*)alloc((size_t)n * sizeof(int));
    int*   row_ptr  = (int*)alloc((size_t)(n + 1) * sizeof(int));
    int*   cursor   = (int*)alloc((size_t)n * sizeof(int));
    int*   partials = (int*)alloc((size_t)(npart > 1024 ? npart : 1024) * sizeof(int));
    int*   perm     = (int*)alloc((size_t)n * sizeof(int));
    float* bhb      = (float*)alloc((size_t)nlayers * D * sizeof(float));
    float* vvb      = (float*)alloc((size_t)nlayers * sizeof(float));
    Edge*  eds      = (Edge*)alloc((size_t)e * sizeof(Edge));

    hipMemsetAsync(counts, 0, (size_t)n * sizeof(int), stream);
    hist_kernel<<<(e + 255) / 256, 256, 0, stream>>>(rows, counts, e);
    partial_kernel<<<npart, 256, 0, stream>>>(counts, partials, n);
    scan_partials<<<1, 1024, 0, stream>>>(partials, npart);
    rowptr_kernel<<<npart, 256, 0, stream>>>(counts, partials, row_ptr, cursor, n, e);
    scatter_kernel<<<(e + 255) / 256, 256, 0, stream>>>(rows, cols, vals, cursor, eds, e);
    block_degsort<<<npart, 256, 0, stream>>>(counts, perm, n);

    bias_prep<<<nlayers, 64, 0, stream>>>(bias, bhb, vvb);
    proj_init<<<(n + 3) / 4, 256, 0, stream>>>(ent, x, logscale, xnorm2, n);

    for (int l = 0; l < nlayers; ++l) {
        logmap_gemm<<<782, 256, 0, stream>>>(x, logscale, W + (size_t)l * D * D, m, n, ntiles);
        int use_act = (l < nlayers - 1) ? 1 : 0;
        aggregate<<<(n + 7) / 8, 256, 0, stream>>>(m, row_ptr, eds, perm, bhb + (size_t)l * D,
                                                   vvb + l, x, logscale, xnorm2, n,
                                                   use_act, (l == nlayers - 1) ? 1 : 0);
    }
}

// Round 9
// 280.432 us; speedup vs baseline: 3.5375x; 1.0722x over previous
//
#include <hip/hip_runtime.h>
#include <math.h>

#define D 128
#define PROJ_EPS 1e-5f
#define MAX_NN (1.0f - PROJ_EPS)
#define MIN_NORM 1e-15f
#define ROWS_PER_BLOCK 2048

struct __align__(8) Edge { int c; float v; };

typedef __attribute__((ext_vector_type(8))) short bf16x8;
typedef __attribute__((ext_vector_type(4))) float f32x4;

__device__ inline unsigned short f2bf(float f) {
    unsigned u = __float_as_uint(f);
    unsigned r = (u + 0x7FFFu + ((u >> 16) & 1u)) >> 16;
    return (unsigned short)r;
}
__device__ inline float bf2f(unsigned short h) {
    return __uint_as_float(((unsigned)h) << 16);
}

__device__ inline float wave_sum(float v) {
#pragma unroll
    for (int off = 32; off; off >>= 1) v += __shfl_xor(v, off, 64);
    return v;
}
// 16-lane-group reductions (xor offsets <16 never cross the group boundary)
__device__ inline float g16sum(float v) {
#pragma unroll
    for (int off = 8; off; off >>= 1) v += __shfl_xor(v, off, 64);
    return v;
}
__device__ inline void g16sum2(float& a, float& b) {
#pragma unroll
    for (int off = 8; off; off >>= 1) {
        a += __shfl_xor(a, off, 64);
        b += __shfl_xor(b, off, 64);
    }
}
__device__ inline float frcp(float x) { return __builtin_amdgcn_rcpf(x); }
__device__ inline float fsqrt_(float x) { return __builtin_amdgcn_sqrtf(x); }
__device__ inline float tanh_pos(float x) {
    float e = __expf(-2.f * x);
    return (1.f - e) * frcp(1.f + e);
}
__device__ inline float tanh_sgn(float x) {
    float ax = fabsf(x);
    float e = __expf(-2.f * ax);
    float r = (1.f - e) * frcp(1.f + e);
    return copysignf(r, x);
}
__device__ inline float atanh_clip(float x) {
    return 0.5f * __logf((1.f + x) * frcp(1.f - x));
}

// ---- packed-f32 pair ops ----
__device__ inline float2 mk2(float a, float b) { float2 r; r.x = a; r.y = b; return r; }
__device__ inline float2 bc2(float a) { return mk2(a, a); }
__device__ inline float2 pk_fma2(float2 a, float2 b, float2 c) {
    float2 d;
    asm("v_pk_fma_f32 %0, %1, %2, %3" : "=v"(d) : "v"(a), "v"(b), "v"(c));
    return d;
}
__device__ inline float2 pk_mul2(float2 a, float2 b) {
    float2 d;
    asm("v_pk_mul_f32 %0, %1, %2" : "=v"(d) : "v"(a), "v"(b));
    return d;
}
__device__ inline float2 up2(unsigned u) {
    uint2 t; t.x = u << 16; t.y = u & 0xffff0000u;
    float2 r; r.x = __uint_as_float(t.x); r.y = __uint_as_float(t.y);
    return r;
}

// ---------------- CSR build ----------------
__global__ void hist_kernel(const int* __restrict__ rows, int* __restrict__ counts, int e) {
    int i = blockIdx.x * blockDim.x + threadIdx.x;
    if (i < e) atomicAdd(&counts[rows[i]], 1);
}

__global__ __launch_bounds__(256) void partial_kernel(const int* __restrict__ counts,
                                                      int* __restrict__ partials, int n) {
    int t = threadIdx.x;
    int start = blockIdx.x * ROWS_PER_BLOCK + t * 8;
    int s = 0;
#pragma unroll
    for (int j = 0; j < 8; ++j) {
        int i = start + j;
        if (i < n) s += counts[i];
    }
    int lane = t & 63, wv = t >> 6;
#pragma unroll
    for (int o = 32; o; o >>= 1) s += __shfl_xor(s, o, 64);
    __shared__ int wsum[4];
    if (lane == 0) wsum[wv] = s;
    __syncthreads();
    if (t == 0) partials[blockIdx.x] = wsum[0] + wsum[1] + wsum[2] + wsum[3];
}

__global__ void scan_partials(int* __restrict__ partials, int npart) {
    __shared__ int buf[1024];
    int t = threadIdx.x;
    int v = (t < npart) ? partials[t] : 0;
    buf[t] = v;
    __syncthreads();
    for (int o = 1; o < 1024; o <<= 1) {
        int x = (t >= o) ? buf[t - o] : 0;
        __syncthreads();
        buf[t] += x;
        __syncthreads();
    }
    if (t < npart) partials[t] = buf[t] - v;
}

__global__ __launch_bounds__(256) void rowptr_kernel(const int* __restrict__ counts,
                                                     const int* __restrict__ partials,
                                                     int* __restrict__ row_ptr,
                                                     int* __restrict__ cursor, int n, int e) {
    int t = threadIdx.x;
    int start = blockIdx.x * ROWS_PER_BLOCK + t * 8;
    int c[8];
    int s = 0;
#pragma unroll
    for (int j = 0; j < 8; ++j) {
        int i = start + j;
        c[j] = (i < n) ? counts[i] : 0;
        s += c[j];
    }
    int lane = t & 63, wv = t >> 6;
    int inc = s;
#pragma unroll
    for (int o = 1; o < 64; o <<= 1) {
        int tt = __shfl_up(inc, o, 64);
        if (lane >= o) inc += tt;
    }
    __shared__ int wsum[4];
    if (lane == 63) wsum[wv] = inc;
    __syncthreads();
    if (t == 0) {
        int acc = 0;
        for (int w = 0; w < 4; ++w) { int tmp = wsum[w]; wsum[w] = acc; acc += tmp; }
    }
    __syncthreads();
    int run = partials[blockIdx.x] + wsum[wv] + (inc - s);
#pragma unroll
    for (int j = 0; j < 8; ++j) {
        int i = start + j;
        if (i < n) {
            row_ptr[i] = run;
            cursor[i] = run;
            run += c[j];
        }
    }
    if (blockIdx.x == 0 && t == 0) row_ptr[n] = e;
}

__global__ void scatter_kernel(const int* __restrict__ rows, const int* __restrict__ cols,
                               const float* __restrict__ vals, int* __restrict__ cursor,
                               Edge* __restrict__ eds, int e) {
    int i = blockIdx.x * blockDim.x + threadIdx.x;
    if (i < e) {
        int r = rows[i];
        int pos = atomicAdd(&cursor[r], 1);
        Edge ed; ed.c = cols[i]; ed.v = vals[i];
        eds[pos] = ed;
    }
}

// ---------------- init: x = proj(ent), logscale, xnorm2 ----------------
__global__ __launch_bounds__(256) void proj_init(const float* __restrict__ ent,
                                                 float* __restrict__ x,
                                                 float* __restrict__ logscale,
                                                 float* __restrict__ xnorm2, int n) {
    int wid = (int)((blockIdx.x * (size_t)blockDim.x + threadIdx.x) >> 6);
    int lane = threadIdx.x & 63;
    if (wid >= n) return;
    float2 v = *(const float2*)(ent + (size_t)wid * D + 2 * lane);
    float nrm = sqrtf(wave_sum(v.x * v.x + v.y * v.y));
    float scale = (nrm > MAX_NN) ? MAX_NN / fmaxf(nrm, MIN_NORM) : 1.0f;
    float px = v.x * scale, py = v.y * scale;
    float n2 = fmaxf(sqrtf(wave_sum(px * px + py * py)), MIN_NORM);
    float nc = fminf(fmaxf(n2, MIN_NORM), MAX_NN);
    float ls = atanhf(nc) / n2;
    *(float2*)(x + (size_t)wid * D + 2 * lane) = make_float2(px, py);
    if (lane == 0) { logscale[wid] = ls; xnorm2[wid] = n2 * n2; }
}

// ---------------- per-layer bias precompute ----------------
__global__ void bias_prep(const float* __restrict__ bias, float* __restrict__ bh,
                          float* __restrict__ vvb) {
    int l = blockIdx.x;
    int lane = threadIdx.x;
    float2 b2 = *(const float2*)(bias + (size_t)l * D + 2 * lane);
    float nn = fmaxf(sqrtf(wave_sum(b2.x * b2.x + b2.y * b2.y)), MIN_NORM);
    float s = tanhf(nn) / nn;
    float bx = b2.x * s, by = b2.y * s;
    float pn = sqrtf(wave_sum(bx * bx + by * by));
    float sc = (pn > MAX_NN) ? MAX_NN / fmaxf(pn, MIN_NORM) : 1.0f;
    bx *= sc; by *= sc;
    float vv = wave_sum(bx * bx + by * by);
    *(float2*)(bh + (size_t)l * D + 2 * lane) = make_float2(bx, by);
    if (lane == 0) vvb[l] = vv;
}

// ---------------- m = (logscale[row] * x[row]) @ W via bf16 MFMA (hi/lo), bf16 output ----
__global__ __launch_bounds__(256, 3) void logmap_gemm(const float* __restrict__ x,
                                                      const float* __restrict__ logscale,
                                                      const float* __restrict__ W,
                                                      unsigned short* __restrict__ m, int n,
                                                      int ntiles) {
    __shared__ char lds[16384];
    const int t = threadIdx.x;
    const int wid = t >> 6, lane = t & 63;
    const int lcol = lane & 15, lkg = lane >> 4;
    const int colbase = wid * 32;

    bf16x8 Bh[4][2], Bl[4][2];
#pragma unroll
    for (int ki = 0; ki < 4; ++ki) {
#pragma unroll
        for (int cf = 0; cf < 2; ++cf) {
            const float* wp = W + (size_t)(ki * 32 + lkg * 8) * D + colbase + cf * 16 + lcol;
#pragma unroll
            for (int e = 0; e < 8; ++e) {
                float f = wp[(size_t)e * D];
                unsigned short h = f2bf(f);
                Bh[ki][cf][e] = (short)h;
                Bl[ki][cf][e] = (short)f2bf(f - bf2f(h));
            }
        }
    }

    for (int tile = blockIdx.x; tile < ntiles; tile += gridDim.x) {
        const int row0 = tile * 32;
        __syncthreads();
#pragma unroll
        for (int p = t; p < 512; p += 256) {
            int fi = p >> 6, ln = p & 63;
            int rf = fi >> 2, ki = fi & 3;
            int row = row0 + rf * 16 + (ln & 15);
            int k0 = ki * 32 + (ln >> 4) * 8;
            float v[8];
            if (row < n) {
                float ls = logscale[row];
                const float* xp = x + (size_t)row * D + k0;
                *(float4*)&v[0] = *(const float4*)xp;
                *(float4*)&v[4] = *(const float4*)(xp + 4);
#pragma unroll
                for (int e = 0; e < 8; ++e) v[e] *= ls;
            } else {
#pragma unroll
                for (int e = 0; e < 8; ++e) v[e] = 0.f;
            }
            bf16x8 hi, lo;
#pragma unroll
            for (int e = 0; e < 8; ++e) {
                unsigned short h = f2bf(v[e]);
                hi[e] = (short)h;
                lo[e] = (short)f2bf(v[e] - bf2f(h));
            }
            *(bf16x8*)(lds + fi * 1024 + ln * 16) = hi;
            *(bf16x8*)(lds + 8192 + fi * 1024 + ln * 16) = lo;
        }
        __syncthreads();

        f32x4 acc[2][2];
#pragma unroll
        for (int rf = 0; rf < 2; ++rf)
#pragma unroll
            for (int cf = 0; cf < 2; ++cf) acc[rf][cf] = (f32x4){0.f, 0.f, 0.f, 0.f};

#pragma unroll
        for (int ki = 0; ki < 4; ++ki) {
            bf16x8 Ah[2], Al[2];
#pragma unroll
            for (int rf = 0; rf < 2; ++rf) {
                Ah[rf] = *(const bf16x8*)(lds + (rf * 4 + ki) * 1024 + lane * 16);
                Al[rf] = *(const bf16x8*)(lds + 8192 + (rf * 4 + ki) * 1024 + lane * 16);
            }
#pragma unroll
            for (int rf = 0; rf < 2; ++rf)
#pragma unroll
                for (int cf = 0; cf < 2; ++cf) {
                    acc[rf][cf] = __builtin_amdgcn_mfma_f32_16x16x32_bf16(Ah[rf], Bh[ki][cf], acc[rf][cf], 0, 0, 0);
                    acc[rf][cf] = __builtin_amdgcn_mfma_f32_16x16x32_bf16(Ah[rf], Bl[ki][cf], acc[rf][cf], 0, 0, 0);
                    acc[rf][cf] = __builtin_amdgcn_mfma_f32_16x16x32_bf16(Al[rf], Bh[ki][cf], acc[rf][cf], 0, 0, 0);
                }
        }

#pragma unroll
        for (int rf = 0; rf < 2; ++rf)
#pragma unroll
            for (int cf = 0; cf < 2; ++cf)
#pragma unroll
                for (int r = 0; r < 4; ++r) {
                    int row = row0 + rf * 16 + lkg * 4 + r;
                    if (row < n)
                        m[(size_t)row * D + colbase + cf * 16 + lcol] = f2bf(acc[rf][cf][r]);
                }
    }
}

// ---------------- aggregate + epilogue: 4 rows/wave (16 lanes x 8 cols each) ----------
__global__ __launch_bounds__(256) void aggregate(const unsigned short* __restrict__ m,
                                                 const int* __restrict__ row_ptr,
                                                 const Edge* __restrict__ eds,
                                                 const float* __restrict__ bh,
                                                 const float* __restrict__ vvb_p,
                                                 float* __restrict__ x,
                                                 float* __restrict__ logscale,
                                                 float* __restrict__ xnorm2,
                                                 int n, int use_act, int last) {
    int wv = (int)((blockIdx.x * (size_t)blockDim.x + threadIdx.x) >> 6);
    int lane = threadIdx.x & 63;
    int q = lane >> 4, li = lane & 15;
    if (wv * 4 >= n) return;
    int r = wv * 4 + q;
    bool active = (r < n);

    int beg = 0, end = 0;
    if (active) { beg = row_ptr[r]; end = row_ptr[r + 1]; }

    const char* mB = (const char*)m + ((size_t)li << 4);
    float2 A01 = bc2(0.f), A23 = bc2(0.f), A45 = bc2(0.f), A67 = bc2(0.f);
    int e = beg;
    for (; e + 4 <= end; e += 4) {
#pragma unroll
        for (int j = 0; j < 4; ++j) {
            Edge ee = eds[e + j];
            uint4 g = *(const uint4*)(mB + ((size_t)(unsigned)ee.c << 8));
            float2 v = bc2(ee.v);
            A01 = pk_fma2(up2(g.x), v, A01); A23 = pk_fma2(up2(g.y), v, A23);
            A45 = pk_fma2(up2(g.z), v, A45); A67 = pk_fma2(up2(g.w), v, A67);
        }
    }
    for (; e < end; ++e) {
        Edge ee = eds[e];
        uint4 g = *(const uint4*)(mB + ((size_t)(unsigned)ee.c << 8));
        float2 v = bc2(ee.v);
        A01 = pk_fma2(up2(g.x), v, A01); A23 = pk_fma2(up2(g.y), v, A23);
        A45 = pk_fma2(up2(g.z), v, A45); A67 = pk_fma2(up2(g.w), v, A67);
    }

    float4 bv0 = *(const float4*)(bh + 8 * li);
    float4 bv1 = *(const float4*)(bh + 8 * li + 4);
    float2 b01 = mk2(bv0.x, bv0.y), b23 = mk2(bv0.z, bv0.w);
    float2 b45 = mk2(bv1.x, bv1.y), b67 = mk2(bv1.z, bv1.w);
    float vvb = *vvb_p;

    float2 daa = pk_fma2(A67, A67, pk_fma2(A45, A45, pk_fma2(A23, A23, pk_mul2(A01, A01))));
    float2 dab = pk_fma2(A67, b67, pk_fma2(A45, b45, pk_fma2(A23, b23, pk_mul2(A01, b01))));
    float saa = daa.x + daa.y, sab = dab.x + dab.y;
    g16sum2(saa, sab);

    float na = fmaxf(fsqrt_(saa), MIN_NORM);
    float th = tanh_pos(na);
    float s1 = th * frcp(na);
    float nh = th;
    if (th > MAX_NN) { s1 *= MAX_NN * frcp(th); nh = MAX_NN; }
    float2 vs1 = bc2(s1);
    float2 H01 = pk_mul2(A01, vs1), H23 = pk_mul2(A23, vs1);
    float2 H45 = pk_mul2(A45, vs1), H67 = pk_mul2(A67, vs1);
    float uu = nh * nh;
    float uv = s1 * sab;

    float ca = 1.f + 2.f * uv + vvb;
    float cb = 1.f - uu;
    float den = fmaxf(1.f + 2.f * uv + uu * vvb, MIN_NORM);
    float nsq = fmaxf(ca * ca * uu + 2.f * ca * cb * uv + cb * cb * vvb, 0.f);
    float rden = frcp(den);
    float n2 = fsqrt_(nsq) * rden;
    float s2 = rden;
    if (n2 > MAX_NN) { s2 *= MAX_NN * frcp(n2); n2 = MAX_NN; }
    float2 vca = bc2(ca), vcb = bc2(cb), vs2 = bc2(s2);
    float2 P01 = pk_mul2(pk_fma2(H01, vca, pk_mul2(b01, vcb)), vs2);
    float2 P23 = pk_mul2(pk_fma2(H23, vca, pk_mul2(b23, vcb)), vs2);
    float2 P45 = pk_mul2(pk_fma2(H45, vca, pk_mul2(b45, vcb)), vs2);
    float2 P67 = pk_mul2(pk_fma2(H67, vca, pk_mul2(b67, vcb)), vs2);

    float4 xa = active ? *(const float4*)(x + (size_t)r * D + 8 * li)
                       : make_float4(0.f, 0.f, 0.f, 0.f);
    float4 xb = active ? *(const float4*)(x + (size_t)r * D + 8 * li + 4)
                       : make_float4(0.f, 0.f, 0.f, 0.f);
    float2 xo01 = mk2(xa.x, xa.y), xo23 = mk2(xa.z, xa.w);
    float2 xo45 = mk2(xb.x, xb.y), xo67 = mk2(xb.z, xb.w);

    float2 Q01, Q23, Q45, Q67;
    float uu3, uv3;
    if (use_act) {
        float nnv = fmaxf(n2, MIN_NORM);
        float nc = fminf(fmaxf(n2, MIN_NORM), MAX_NN);
        float ls2 = atanh_clip(nc) * frcp(nnv);
        float2 vls = bc2(ls2);
        float2 Z01 = pk_mul2(P01, vls), Z23 = pk_mul2(P23, vls);
        float2 Z45 = pk_mul2(P45, vls), Z67 = pk_mul2(P67, vls);
        float2 T01 = mk2(tanh_sgn(Z01.x), tanh_sgn(Z01.y));
        float2 T23 = mk2(tanh_sgn(Z23.x), tanh_sgn(Z23.y));
        float2 T45 = mk2(tanh_sgn(Z45.x), tanh_sgn(Z45.y));
        float2 T67 = mk2(tanh_sgn(Z67.x), tanh_sgn(Z67.y));
        float2 dtt = pk_fma2(T67, T67, pk_fma2(T45, T45, pk_fma2(T23, T23, pk_mul2(T01, T01))));
        float2 dtx = pk_fma2(T67, xo67, pk_fma2(T45, xo45, pk_fma2(T23, xo23, pk_mul2(T01, xo01))));
        float stt = dtt.x + dtt.y, stx = dtx.x + dtx.y;
        g16sum2(stt, stx);
        float n3 = fmaxf(fsqrt_(stt), MIN_NORM);
        float th3 = tanh_pos(n3);
        float s3 = th3 * frcp(n3);
        float nh3 = th3;
        if (th3 > MAX_NN) { s3 *= MAX_NN * frcp(th3); nh3 = MAX_NN; }
        float2 vs3 = bc2(s3);
        Q01 = pk_mul2(T01, vs3); Q23 = pk_mul2(T23, vs3);
        Q45 = pk_mul2(T45, vs3); Q67 = pk_mul2(T67, vs3);
        uu3 = nh3 * nh3;
        uv3 = s3 * stx;
    } else {
        float2 dpx = pk_fma2(P67, xo67, pk_fma2(P45, xo45, pk_fma2(P23, xo23, pk_mul2(P01, xo01))));
        float suv = g16sum(dpx.x + dpx.y);
        Q01 = P01; Q23 = P23; Q45 = P45; Q67 = P67;
        uu3 = n2 * n2;
        uv3 = suv;
    }

    float vv = active ? xnorm2[r] : 0.f;
    ca = 1.f + 2.f * uv3 + vv;
    cb = 1.f - uu3;
    den = fmaxf(1.f + 2.f * uv3 + uu3 * vv, MIN_NORM);
    nsq = fmaxf(ca * ca * uu3 + 2.f * ca * cb * uv3 + cb * cb * vv, 0.f);
    rden = frcp(den);
    float n4 = fsqrt_(nsq) * rden;
    float s4 = rden;
    if (n4 > MAX_NN) { s4 *= MAX_NN * frcp(n4); n4 = MAX_NN; }
    float2 vca2 = bc2(ca), vcb2 = bc2(cb), vs4 = bc2(s4);
    float2 O01 = pk_mul2(pk_fma2(Q01, vca2, pk_mul2(xo01, vcb2)), vs4);
    float2 O23 = pk_mul2(pk_fma2(Q23, vca2, pk_mul2(xo23, vcb2)), vs4);
    float2 O45 = pk_mul2(pk_fma2(Q45, vca2, pk_mul2(xo45, vcb2)), vs4);
    float2 O67 = pk_mul2(pk_fma2(Q67, vca2, pk_mul2(xo67, vcb2)), vs4);

    if (active) {
        *(float4*)(x + (size_t)r * D + 8 * li) = make_float4(O01.x, O01.y, O23.x, O23.y);
        *(float4*)(x + (size_t)r * D + 8 * li + 4) = make_float4(O45.x, O45.y, O67.x, O67.y);
        if (li == 0) {
            xnorm2[r] = n4 * n4;
            if (!last) {
                float nnv = fmaxf(n4, MIN_NORM);
                float nc = fminf(fmaxf(n4, MIN_NORM), MAX_NN);
                logscale[r] = atanh_clip(nc) * frcp(nnv);
            }
        }
    }
}

extern "C" void kernel_launch(void* const* d_in, const int* in_sizes, int n_in,
                              void* d_out, int out_size, void* d_ws, size_t ws_size,
                              hipStream_t stream) {
    const float* ent  = (const float*)d_in[0];
    const float* W    = (const float*)d_in[1];
    const float* bias = (const float*)d_in[2];
    const int* rows   = (const int*)d_in[3];
    const int* cols   = (const int*)d_in[4];
    const float* vals = (const float*)d_in[5];
    float* x = (float*)d_out;

    const int n = in_sizes[0] / D;
    const int e = in_sizes[3];
    const int nlayers = in_sizes[1] / (D * D);
    const int npart = (n + ROWS_PER_BLOCK - 1) / ROWS_PER_BLOCK;
    const int ntiles = (n + 31) / 32;

    char* ws = (char*)d_ws;
    size_t off = 0;
    auto alloc = [&](size_t bytes) {
        void* p = ws + off;
        off += (bytes + 255) & ~(size_t)255;
        return p;
    };
    unsigned short* m = (unsigned short*)alloc((size_t)n * D * sizeof(unsigned short));
    float* logscale = (float*)alloc((size_t)n * sizeof(float));
    float* xnorm2   = (float*)alloc((size_t)n * sizeof(float));
    int*   counts   = (int*)alloc((size_t)n * sizeof(int));
    int*   row_ptr  = (int*)alloc((size_t)(n + 1) * sizeof(int));
    int*   cursor   = (int*)alloc((size_t)n * sizeof(int));
    int*   partials = (int*)alloc((size_t)(npart > 1024 ? npart : 1024) * sizeof(int));
    float* bhb      = (float*)alloc((size_t)nlayers * D * sizeof(float));
    float* vvb      = (float*)alloc((size_t)nlayers * sizeof(float));
    Edge*  eds      = (Edge*)alloc((size_t)e * sizeof(Edge));

    hipMemsetAsync(counts, 0, (size_t)n * sizeof(int), stream);
    hist_kernel<<<(e + 255) / 256, 256, 0, stream>>>(rows, counts, e);
    partial_kernel<<<npart, 256, 0, stream>>>(counts, partials, n);
    scan_partials<<<1, 1024, 0, stream>>>(partials, npart);
    rowptr_kernel<<<npart, 256, 0, stream>>>(counts, partials, row_ptr, cursor, n, e);
    scatter_kernel<<<(e + 255) / 256, 256, 0, stream>>>(rows, cols, vals, cursor, eds, e);

    bias_prep<<<nlayers, 64, 0, stream>>>(bias, bhb, vvb);
    proj_init<<<(n + 3) / 4, 256, 0, stream>>>(ent, x, logscale, xnorm2, n);

    for (int l = 0; l < nlayers; ++l) {
        logmap_gemm<<<782, 256, 0, stream>>>(x, logscale, W + (size_t)l * D * D, m, n, ntiles);
        int use_act = (l < nlayers - 1) ? 1 : 0;
        // 4 waves/block, 4 rows/wave -> 16 rows per block
        aggregate<<<(n + 15) / 16, 256, 0, stream>>>(m, row_ptr, eds, bhb + (size_t)l * D,
                                                     vvb + l, x, logscale, xnorm2, n,
                                                     use_act, (l == nlayers - 1) ? 1 : 0);
    }
}

// Round 10
// 271.053 us; speedup vs baseline: 3.6599x; 1.0346x over previous
//
#include <hip/hip_runtime.h>
#include <math.h>

#define D 128
#define PROJ_EPS 1e-5f
#define MAX_NN (1.0f - PROJ_EPS)
#define MIN_NORM 1e-15f
#define ROWS_PER_BLOCK 2048

struct __align__(8) Edge { int c; float v; };

typedef __attribute__((ext_vector_type(8))) short bf16x8;
typedef __attribute__((ext_vector_type(4))) float f32x4;

// packed f32->bf16 RNE convert: dst.lo = bf16(a), dst.hi = bf16(b)
__device__ inline unsigned cvt_pk_bf16(float a, float b) {
    unsigned r;
    asm("v_cvt_pk_bf16_f32 %0, %1, %2" : "=v"(r) : "v"(a), "v"(b));
    return r;
}

__device__ inline float wave_sum(float v) {
#pragma unroll
    for (int off = 32; off; off >>= 1) v += __shfl_xor(v, off, 64);
    return v;
}
// 16-lane-group reductions
__device__ inline float g16sum(float v) {
#pragma unroll
    for (int off = 8; off; off >>= 1) v += __shfl_xor(v, off, 64);
    return v;
}
__device__ inline void g16sum2(float& a, float& b) {
#pragma unroll
    for (int off = 8; off; off >>= 1) {
        a += __shfl_xor(a, off, 64);
        b += __shfl_xor(b, off, 64);
    }
}
__device__ inline float frcp(float x) { return __builtin_amdgcn_rcpf(x); }
__device__ inline float fsqrt_(float x) { return __builtin_amdgcn_sqrtf(x); }
__device__ inline float tanh_pos(float x) {
    float e = __expf(-2.f * x);
    return (1.f - e) * frcp(1.f + e);
}
__device__ inline float tanh_sgn(float x) {
    float ax = fabsf(x);
    float e = __expf(-2.f * ax);
    float r = (1.f - e) * frcp(1.f + e);
    return copysignf(r, x);
}
__device__ inline float atanh_clip(float x) {
    return 0.5f * __logf((1.f + x) * frcp(1.f - x));
}

// ---- packed-f32 pair ops ----
__device__ inline float2 mk2(float a, float b) { float2 r; r.x = a; r.y = b; return r; }
__device__ inline float2 bc2(float a) { return mk2(a, a); }
__device__ inline float2 pk_fma2(float2 a, float2 b, float2 c) {
    float2 d;
    asm("v_pk_fma_f32 %0, %1, %2, %3" : "=v"(d) : "v"(a), "v"(b), "v"(c));
    return d;
}
__device__ inline float2 pk_mul2(float2 a, float2 b) {
    float2 d;
    asm("v_pk_mul_f32 %0, %1, %2" : "=v"(d) : "v"(a), "v"(b));
    return d;
}
__device__ inline float2 up2(unsigned u) {
    uint2 t; t.x = u << 16; t.y = u & 0xffff0000u;
    float2 r; r.x = __uint_as_float(t.x); r.y = __uint_as_float(t.y);
    return r;
}

// ---------------- CSR build ----------------
__global__ void hist_kernel(const int* __restrict__ rows, int* __restrict__ counts, int e) {
    int i = blockIdx.x * blockDim.x + threadIdx.x;
    if (i < e) atomicAdd(&counts[rows[i]], 1);
}

// partial sums of PADDED counts (each row rounded up to multiple of 4)
__global__ __launch_bounds__(256) void partial_kernel(const int* __restrict__ counts,
                                                      int* __restrict__ partials, int n) {
    int t = threadIdx.x;
    int start = blockIdx.x * ROWS_PER_BLOCK + t * 8;
    int s = 0;
#pragma unroll
    for (int j = 0; j < 8; ++j) {
        int i = start + j;
        if (i < n) s += (counts[i] + 3) & ~3;
    }
    int lane = t & 63, wv = t >> 6;
#pragma unroll
    for (int o = 32; o; o >>= 1) s += __shfl_xor(s, o, 64);
    __shared__ int wsum[4];
    if (lane == 0) wsum[wv] = s;
    __syncthreads();
    if (t == 0) partials[blockIdx.x] = wsum[0] + wsum[1] + wsum[2] + wsum[3];
}

__global__ void scan_partials(int* __restrict__ partials, int npart) {
    __shared__ int buf[1024];
    int t = threadIdx.x;
    int v = (t < npart) ? partials[t] : 0;
    buf[t] = v;
    __syncthreads();
    for (int o = 1; o < 1024; o <<= 1) {
        int x = (t >= o) ? buf[t - o] : 0;
        __syncthreads();
        buf[t] += x;
        __syncthreads();
    }
    if (t < npart) partials[t] = buf[t] - v;
}

__global__ __launch_bounds__(256) void rowptr_kernel(const int* __restrict__ counts,
                                                     const int* __restrict__ partials,
                                                     int* __restrict__ row_ptr,
                                                     int* __restrict__ cursor, int n) {
    int t = threadIdx.x;
    int start = blockIdx.x * ROWS_PER_BLOCK + t * 8;
    int c[8];
    int s = 0;
#pragma unroll
    for (int j = 0; j < 8; ++j) {
        int i = start + j;
        c[j] = (i < n) ? ((counts[i] + 3) & ~3) : 0;
        s += c[j];
    }
    int lane = t & 63, wv = t >> 6;
    int inc = s;
#pragma unroll
    for (int o = 1; o < 64; o <<= 1) {
        int tt = __shfl_up(inc, o, 64);
        if (lane >= o) inc += tt;
    }
    __shared__ int wsum[4];
    if (lane == 63) wsum[wv] = inc;
    __syncthreads();
    if (t == 0) {
        int acc = 0;
        for (int w = 0; w < 4; ++w) { int tmp = wsum[w]; wsum[w] = acc; acc += tmp; }
    }
    __syncthreads();
    int run = partials[blockIdx.x] + wsum[wv] + (inc - s);
#pragma unroll
    for (int j = 0; j < 8; ++j) {
        int i = start + j;
        if (i < n) {
            row_ptr[i] = run;
            cursor[i] = run;
            run += c[j];
            if (i == n - 1) row_ptr[n] = run;
        }
    }
}

__global__ void scatter_kernel(const int* __restrict__ rows, const int* __restrict__ cols,
                               const float* __restrict__ vals, int* __restrict__ cursor,
                               Edge* __restrict__ eds, int e) {
    int i = blockIdx.x * blockDim.x + threadIdx.x;
    if (i < e) {
        int r = rows[i];
        int pos = atomicAdd(&cursor[r], 1);
        Edge ed; ed.c = cols[i]; ed.v = vals[i];
        eds[pos] = ed;
    }
}

// ---------------- init: x = proj(ent), logscale, xnorm2 ----------------
__global__ __launch_bounds__(256) void proj_init(const float* __restrict__ ent,
                                                 float* __restrict__ x,
                                                 float* __restrict__ logscale,
                                                 float* __restrict__ xnorm2, int n) {
    int wid = (int)((blockIdx.x * (size_t)blockDim.x + threadIdx.x) >> 6);
    int lane = threadIdx.x & 63;
    if (wid >= n) return;
    float2 v = *(const float2*)(ent + (size_t)wid * D + 2 * lane);
    float nrm = sqrtf(wave_sum(v.x * v.x + v.y * v.y));
    float scale = (nrm > MAX_NN) ? MAX_NN / fmaxf(nrm, MIN_NORM) : 1.0f;
    float px = v.x * scale, py = v.y * scale;
    float n2 = fmaxf(sqrtf(wave_sum(px * px + py * py)), MIN_NORM);
    float nc = fminf(fmaxf(n2, MIN_NORM), MAX_NN);
    float ls = atanhf(nc) / n2;
    *(float2*)(x + (size_t)wid * D + 2 * lane) = make_float2(px, py);
    if (lane == 0) { logscale[wid] = ls; xnorm2[wid] = n2 * n2; }
}

// ---------------- per-layer bias precompute ----------------
__global__ void bias_prep(const float* __restrict__ bias, float* __restrict__ bh,
                          float* __restrict__ vvb) {
    int l = blockIdx.x;
    int lane = threadIdx.x;
    float2 b2 = *(const float2*)(bias + (size_t)l * D + 2 * lane);
    float nn = fmaxf(sqrtf(wave_sum(b2.x * b2.x + b2.y * b2.y)), MIN_NORM);
    float s = tanhf(nn) / nn;
    float bx = b2.x * s, by = b2.y * s;
    float pn = sqrtf(wave_sum(bx * bx + by * by));
    float sc = (pn > MAX_NN) ? MAX_NN / fmaxf(pn, MIN_NORM) : 1.0f;
    bx *= sc; by *= sc;
    float vv = wave_sum(bx * bx + by * by);
    *(float2*)(bh + (size_t)l * D + 2 * lane) = make_float2(bx, by);
    if (lane == 0) vvb[l] = vv;
}

// ---------------- m = (logscale[row] * x[row]) @ W via bf16 MFMA (hi/lo), bf16 output ----
__global__ __launch_bounds__(256, 3) void logmap_gemm(const float* __restrict__ x,
                                                      const float* __restrict__ logscale,
                                                      const float* __restrict__ W,
                                                      unsigned short* __restrict__ m, int n,
                                                      int ntiles) {
    __shared__ char lds[16384];
    const int t = threadIdx.x;
    const int wid = t >> 6, lane = t & 63;
    const int lcol = lane & 15, lkg = lane >> 4;
    const int colbase = wid * 32;

    bf16x8 Bh[4][2], Bl[4][2];
#pragma unroll
    for (int ki = 0; ki < 4; ++ki) {
#pragma unroll
        for (int cf = 0; cf < 2; ++cf) {
            const float* wp = W + (size_t)(ki * 32 + lkg * 8) * D + colbase + cf * 16 + lcol;
            float f[8];
#pragma unroll
            for (int e2 = 0; e2 < 8; ++e2) f[e2] = wp[(size_t)e2 * D];
            unsigned hw[4], lw[4];
#pragma unroll
            for (int p = 0; p < 4; ++p) {
                float a = f[2 * p], b = f[2 * p + 1];
                unsigned h = cvt_pk_bf16(a, b);
                float ha = __uint_as_float(h << 16);
                float hb = __uint_as_float(h & 0xffff0000u);
                hw[p] = h;
                lw[p] = cvt_pk_bf16(a - ha, b - hb);
            }
            uint4 uh = make_uint4(hw[0], hw[1], hw[2], hw[3]);
            uint4 ul = make_uint4(lw[0], lw[1], lw[2], lw[3]);
            Bh[ki][cf] = *(bf16x8*)&uh;
            Bl[ki][cf] = *(bf16x8*)&ul;
        }
    }

    for (int tile = blockIdx.x; tile < ntiles; tile += gridDim.x) {
        const int row0 = tile * 32;
        __syncthreads();
#pragma unroll
        for (int p = t; p < 512; p += 256) {
            int fi = p >> 6, ln = p & 63;
            int rf = fi >> 2, ki = fi & 3;
            int row = row0 + rf * 16 + (ln & 15);
            int k0 = ki * 32 + (ln >> 4) * 8;
            float v[8];
            if (row < n) {
                float ls = logscale[row];
                const float* xp = x + (size_t)row * D + k0;
                *(float4*)&v[0] = *(const float4*)xp;
                *(float4*)&v[4] = *(const float4*)(xp + 4);
#pragma unroll
                for (int e2 = 0; e2 < 8; ++e2) v[e2] *= ls;
            } else {
#pragma unroll
                for (int e2 = 0; e2 < 8; ++e2) v[e2] = 0.f;
            }
            unsigned hv[4], lv[4];
#pragma unroll
            for (int pp = 0; pp < 4; ++pp) {
                float a = v[2 * pp], b = v[2 * pp + 1];
                unsigned h = cvt_pk_bf16(a, b);
                float ha = __uint_as_float(h << 16);
                float hb = __uint_as_float(h & 0xffff0000u);
                hv[pp] = h;
                lv[pp] = cvt_pk_bf16(a - ha, b - hb);
            }
            *(uint4*)(lds + fi * 1024 + ln * 16) = make_uint4(hv[0], hv[1], hv[2], hv[3]);
            *(uint4*)(lds + 8192 + fi * 1024 + ln * 16) = make_uint4(lv[0], lv[1], lv[2], lv[3]);
        }
        __syncthreads();

        f32x4 acc[2][2];
#pragma unroll
        for (int rf = 0; rf < 2; ++rf)
#pragma unroll
            for (int cf = 0; cf < 2; ++cf) acc[rf][cf] = (f32x4){0.f, 0.f, 0.f, 0.f};

#pragma unroll
        for (int ki = 0; ki < 4; ++ki) {
            bf16x8 Ah[2], Al[2];
#pragma unroll
            for (int rf = 0; rf < 2; ++rf) {
                Ah[rf] = *(const bf16x8*)(lds + (rf * 4 + ki) * 1024 + lane * 16);
                Al[rf] = *(const bf16x8*)(lds + 8192 + (rf * 4 + ki) * 1024 + lane * 16);
            }
#pragma unroll
            for (int rf = 0; rf < 2; ++rf)
#pragma unroll
                for (int cf = 0; cf < 2; ++cf) {
                    acc[rf][cf] = __builtin_amdgcn_mfma_f32_16x16x32_bf16(Ah[rf], Bh[ki][cf], acc[rf][cf], 0, 0, 0);
                    acc[rf][cf] = __builtin_amdgcn_mfma_f32_16x16x32_bf16(Ah[rf], Bl[ki][cf], acc[rf][cf], 0, 0, 0);
                    acc[rf][cf] = __builtin_amdgcn_mfma_f32_16x16x32_bf16(Al[rf], Bh[ki][cf], acc[rf][cf], 0, 0, 0);
                }
        }

#pragma unroll
        for (int rf = 0; rf < 2; ++rf)
#pragma unroll
            for (int cf = 0; cf < 2; ++cf)
#pragma unroll
                for (int pr = 0; pr < 2; ++pr) {
                    unsigned u = cvt_pk_bf16(acc[rf][cf][2 * pr], acc[rf][cf][2 * pr + 1]);
                    int row = row0 + rf * 16 + lkg * 4 + 2 * pr;
                    int col = colbase + cf * 16 + lcol;
                    if (row < n) m[(size_t)row * D + col] = (unsigned short)u;
                    if (row + 1 < n) m[(size_t)(row + 1) * D + col] = (unsigned short)(u >> 16);
                }
    }
}

// ---------------- aggregate + epilogue: 4 rows/wave, padded edge lists ----------
__global__ __launch_bounds__(256) void aggregate(const unsigned short* __restrict__ m,
                                                 const int* __restrict__ row_ptr,
                                                 const Edge* __restrict__ eds,
                                                 const float* __restrict__ bh,
                                                 const float* __restrict__ vvb_p,
                                                 float* __restrict__ x,
                                                 float* __restrict__ logscale,
                                                 float* __restrict__ xnorm2,
                                                 int n, int use_act, int last) {
    int wv = (int)((blockIdx.x * (size_t)blockDim.x + threadIdx.x) >> 6);
    int lane = threadIdx.x & 63;
    int q = lane >> 4, li = lane & 15;
    if (wv * 4 >= n) return;
    int r = wv * 4 + q;
    bool active = (r < n);

    int beg = 0, end = 0;
    if (active) { beg = row_ptr[r]; end = row_ptr[r + 1]; }

    // hoist residual-path loads above the gather loop (independent, hides latency)
    float vv = active ? xnorm2[r] : 0.f;
    float4 xa = active ? *(const float4*)(x + (size_t)r * D + 8 * li)
                       : make_float4(0.f, 0.f, 0.f, 0.f);
    float4 xb = active ? *(const float4*)(x + (size_t)r * D + 8 * li + 4)
                       : make_float4(0.f, 0.f, 0.f, 0.f);

    const char* mB = (const char*)m + ((size_t)li << 4);
    float2 A01 = bc2(0.f), A23 = bc2(0.f), A45 = bc2(0.f), A67 = bc2(0.f);
    int e = beg;
    // padded lists: (end-beg) % 4 == 0; dummy slots have c=0, v=0 (exact no-op)
    for (; e + 8 <= end; e += 8) {
#pragma unroll
        for (int j = 0; j < 8; ++j) {
            Edge ee = eds[e + j];
            uint4 g = *(const uint4*)(mB + ((size_t)(unsigned)ee.c << 8));
            float2 v = bc2(ee.v);
            A01 = pk_fma2(up2(g.x), v, A01); A23 = pk_fma2(up2(g.y), v, A23);
            A45 = pk_fma2(up2(g.z), v, A45); A67 = pk_fma2(up2(g.w), v, A67);
        }
    }
    if (e < end) {
#pragma unroll
        for (int j = 0; j < 4; ++j) {
            Edge ee = eds[e + j];
            uint4 g = *(const uint4*)(mB + ((size_t)(unsigned)ee.c << 8));
            float2 v = bc2(ee.v);
            A01 = pk_fma2(up2(g.x), v, A01); A23 = pk_fma2(up2(g.y), v, A23);
            A45 = pk_fma2(up2(g.z), v, A45); A67 = pk_fma2(up2(g.w), v, A67);
        }
    }

    float4 bv0 = *(const float4*)(bh + 8 * li);
    float4 bv1 = *(const float4*)(bh + 8 * li + 4);
    float2 b01 = mk2(bv0.x, bv0.y), b23 = mk2(bv0.z, bv0.w);
    float2 b45 = mk2(bv1.x, bv1.y), b67 = mk2(bv1.z, bv1.w);
    float vvb = *vvb_p;

    float2 daa = pk_fma2(A67, A67, pk_fma2(A45, A45, pk_fma2(A23, A23, pk_mul2(A01, A01))));
    float2 dab = pk_fma2(A67, b67, pk_fma2(A45, b45, pk_fma2(A23, b23, pk_mul2(A01, b01))));
    float saa = daa.x + daa.y, sab = dab.x + dab.y;
    g16sum2(saa, sab);

    float na = fmaxf(fsqrt_(saa), MIN_NORM);
    float th = tanh_pos(na);
    float s1 = th * frcp(na);
    float nh = th;
    if (th > MAX_NN) { s1 *= MAX_NN * frcp(th); nh = MAX_NN; }
    float2 vs1 = bc2(s1);
    float2 H01 = pk_mul2(A01, vs1), H23 = pk_mul2(A23, vs1);
    float2 H45 = pk_mul2(A45, vs1), H67 = pk_mul2(A67, vs1);
    float uu = nh * nh;
    float uv = s1 * sab;

    float ca = 1.f + 2.f * uv + vvb;
    float cb = 1.f - uu;
    float den = fmaxf(1.f + 2.f * uv + uu * vvb, MIN_NORM);
    float nsq = fmaxf(ca * ca * uu + 2.f * ca * cb * uv + cb * cb * vvb, 0.f);
    float rden = frcp(den);
    float n2 = fsqrt_(nsq) * rden;
    float s2 = rden;
    if (n2 > MAX_NN) { s2 *= MAX_NN * frcp(n2); n2 = MAX_NN; }
    float2 vca = bc2(ca), vcb = bc2(cb), vs2 = bc2(s2);
    float2 P01 = pk_mul2(pk_fma2(H01, vca, pk_mul2(b01, vcb)), vs2);
    float2 P23 = pk_mul2(pk_fma2(H23, vca, pk_mul2(b23, vcb)), vs2);
    float2 P45 = pk_mul2(pk_fma2(H45, vca, pk_mul2(b45, vcb)), vs2);
    float2 P67 = pk_mul2(pk_fma2(H67, vca, pk_mul2(b67, vcb)), vs2);

    float2 xo01 = mk2(xa.x, xa.y), xo23 = mk2(xa.z, xa.w);
    float2 xo45 = mk2(xb.x, xb.y), xo67 = mk2(xb.z, xb.w);

    float2 Q01, Q23, Q45, Q67;
    float uu3, uv3;
    if (use_act) {
        float nnv = fmaxf(n2, MIN_NORM);
        float nc = fminf(fmaxf(n2, MIN_NORM), MAX_NN);
        float ls2 = atanh_clip(nc) * frcp(nnv);
        float2 vls = bc2(ls2);
        float2 Z01 = pk_mul2(P01, vls), Z23 = pk_mul2(P23, vls);
        float2 Z45 = pk_mul2(P45, vls), Z67 = pk_mul2(P67, vls);
        float2 T01 = mk2(tanh_sgn(Z01.x), tanh_sgn(Z01.y));
        float2 T23 = mk2(tanh_sgn(Z23.x), tanh_sgn(Z23.y));
        float2 T45 = mk2(tanh_sgn(Z45.x), tanh_sgn(Z45.y));
        float2 T67 = mk2(tanh_sgn(Z67.x), tanh_sgn(Z67.y));
        float2 dtt = pk_fma2(T67, T67, pk_fma2(T45, T45, pk_fma2(T23, T23, pk_mul2(T01, T01))));
        float2 dtx = pk_fma2(T67, xo67, pk_fma2(T45, xo45, pk_fma2(T23, xo23, pk_mul2(T01, xo01))));
        float stt = dtt.x + dtt.y, stx = dtx.x + dtx.y;
        g16sum2(stt, stx);
        float n3 = fmaxf(fsqrt_(stt), MIN_NORM);
        float th3 = tanh_pos(n3);
        float s3 = th3 * frcp(n3);
        float nh3 = th3;
        if (th3 > MAX_NN) { s3 *= MAX_NN * frcp(th3); nh3 = MAX_NN; }
        float2 vs3 = bc2(s3);
        Q01 = pk_mul2(T01, vs3); Q23 = pk_mul2(T23, vs3);
        Q45 = pk_mul2(T45, vs3); Q67 = pk_mul2(T67, vs3);
        uu3 = nh3 * nh3;
        uv3 = s3 * stx;
    } else {
        float2 dpx = pk_fma2(P67, xo67, pk_fma2(P45, xo45, pk_fma2(P23, xo23, pk_mul2(P01, xo01))));
        float suv = g16sum(dpx.x + dpx.y);
        Q01 = P01; Q23 = P23; Q45 = P45; Q67 = P67;
        uu3 = n2 * n2;
        uv3 = suv;
    }

    ca = 1.f + 2.f * uv3 + vv;
    cb = 1.f - uu3;
    den = fmaxf(1.f + 2.f * uv3 + uu3 * vv, MIN_NORM);
    nsq = fmaxf(ca * ca * uu3 + 2.f * ca * cb * uv3 + cb * cb * vv, 0.f);
    rden = frcp(den);
    float n4 = fsqrt_(nsq) * rden;
    float s4 = rden;
    if (n4 > MAX_NN) { s4 *= MAX_NN * frcp(n4); n4 = MAX_NN; }
    float2 vca2 = bc2(ca), vcb2 = bc2(cb), vs4 = bc2(s4);
    float2 O01 = pk_mul2(pk_fma2(Q01, vca2, pk_mul2(xo01, vcb2)), vs4);
    float2 O23 = pk_mul2(pk_fma2(Q23, vca2, pk_mul2(xo23, vcb2)), vs4);
    float2 O45 = pk_mul2(pk_fma2(Q45, vca2, pk_mul2(xo45, vcb2)), vs4);
    float2 O67 = pk_mul2(pk_fma2(Q67, vca2, pk_mul2(xo67, vcb2)), vs4);

    if (active) {
        *(float4*)(x + (size_t)r * D + 8 * li) = make_float4(O01.x, O01.y, O23.x, O23.y);
        *(float4*)(x + (size_t)r * D + 8 * li + 4) = make_float4(O45.x, O45.y, O67.x, O67.y);
        if (li == 0) {
            xnorm2[r] = n4 * n4;
            if (!last) {
                float nnv = fmaxf(n4, MIN_NORM);
                float nc = fminf(fmaxf(n4, MIN_NORM), MAX_NN);
                logscale[r] = atanh_clip(nc) * frcp(nnv);
            }
        }
    }
}

extern "C" void kernel_launch(void* const* d_in, const int* in_sizes, int n_in,
                              void* d_out, int out_size, void* d_ws, size_t ws_size,
                              hipStream_t stream) {
    const float* ent  = (const float*)d_in[0];
    const float* W    = (const float*)d_in[1];
    const float* bias = (const float*)d_in[2];
    const int* rows   = (const int*)d_in[3];
    const int* cols   = (const int*)d_in[4];
    const float* vals = (const float*)d_in[5];
    float* x = (float*)d_out;

    const int n = in_sizes[0] / D;
    const int e = in_sizes[3];
    const int nlayers = in_sizes[1] / (D * D);
    const int npart = (n + ROWS_PER_BLOCK - 1) / ROWS_PER_BLOCK;
    const int ntiles = (n + 31) / 32;
    const size_t e_cap = (size_t)e + 3u * (size_t)n;  // padding upper bound

    char* ws = (char*)d_ws;
    size_t off = 0;
    auto alloc = [&](size_t bytes) {
        void* p = ws + off;
        off += (bytes + 255) & ~(size_t)255;
        return p;
    };
    unsigned short* m = (unsigned short*)alloc((size_t)n * D * sizeof(unsigned short));
    float* logscale = (float*)alloc((size_t)n * sizeof(float));
    float* xnorm2   = (float*)alloc((size_t)n * sizeof(float));
    int*   counts   = (int*)alloc((size_t)n * sizeof(int));
    int*   row_ptr  = (int*)alloc((size_t)(n + 1) * sizeof(int));
    int*   cursor   = (int*)alloc((size_t)n * sizeof(int));
    int*   partials = (int*)alloc((size_t)(npart > 1024 ? npart : 1024) * sizeof(int));
    float* bhb      = (float*)alloc((size_t)nlayers * D * sizeof(float));
    float* vvb      = (float*)alloc((size_t)nlayers * sizeof(float));
    Edge*  eds      = (Edge*)alloc(e_cap * sizeof(Edge));

    hipMemsetAsync(counts, 0, (size_t)n * sizeof(int), stream);
    hipMemsetAsync(eds, 0, e_cap * sizeof(Edge), stream);  // dummy pad slots = {c=0,v=0}
    hist_kernel<<<(e + 255) / 256, 256, 0, stream>>>(rows, counts, e);
    partial_kernel<<<npart, 256, 0, stream>>>(counts, partials, n);
    scan_partials<<<1, 1024, 0, stream>>>(partials, npart);
    rowptr_kernel<<<npart, 256, 0, stream>>>(counts, partials, row_ptr, cursor, n);
    scatter_kernel<<<(e + 255) / 256, 256, 0, stream>>>(rows, cols, vals, cursor, eds, e);

    bias_prep<<<nlayers, 64, 0, stream>>>(bias, bhb, vvb);
    proj_init<<<(n + 3) / 4, 256, 0, stream>>>(ent, x, logscale, xnorm2, n);

    for (int l = 0; l < nlayers; ++l) {
        logmap_gemm<<<782, 256, 0, stream>>>(x, logscale, W + (size_t)l * D * D, m, n, ntiles);
        int use_act = (l < nlayers - 1) ? 1 : 0;
        aggregate<<<(n + 15) / 16, 256, 0, stream>>>(m, row_ptr, eds, bhb + (size_t)l * D,
                                                     vvb + l, x, logscale, xnorm2, n,
                                                     use_act, (l == nlayers - 1) ? 1 : 0);
    }
}